// Round 10
// baseline (289.891 us; speedup 1.0000x reference)
//
#include <hip/hip_runtime.h>

#define NN 100000
#define NE 640000
#define GB1 ((NN + 63) / 64)   // 1563 gemm blocks (64 rows each)
#define HB1 (NE / 4 / 256)     // 625 hist blocks (4 edges/thread)

typedef unsigned int uint32;
typedef __attribute__((ext_vector_type(8))) short short8;
typedef __attribute__((ext_vector_type(4))) float f32x4;

static __device__ __forceinline__ ushort f2bf(float f) {
    uint32 u = __float_as_uint(f);
    u = (u + 0x7fffu + ((u >> 16) & 1u)) >> 16;
    return (ushort)u;
}
static __device__ __forceinline__ float bf2f(uint32 bits16) {
    return __uint_as_float(bits16 << 16);
}
static __device__ __forceinline__ uint32 pack2(float a, float b) {
    return (uint32)f2bf(a) | ((uint32)f2bf(b) << 16);
}

// ---------------- GEMM body: H(bf16) = X(f32->bf16) @ W(f32, inline-transposed) ----------------
// 256 thr (4 waves), 64 rows x NOUT cols. K=128 fully staged, 1 barrier.
// W^T staged inline: coalesced float4 reads of W[128][NOUT], scattered 2B LDS writes.
// LDS XOR-swizzle: 16B-block index ^= (row&7) => conflict-free fragment reads.
template <int NOUT>
static __device__ __forceinline__ void gemm_body(const float* __restrict__ X,
                                                 const float* __restrict__ W,
                                                 ushort* __restrict__ H, int N,
                                                 int bid, int tid, char* smem) {
    char* xs = smem;              // [64 rows][128 k] bf16, swizzled
    char* wt = smem + 64 * 256;   // [NOUT cols][128 k] bf16, swizzled
    const int row0 = bid * 64;

    // stage W^T: id over float4s of W (k-major), scatter 4 bf16 to col-rows
    const float4* W4 = reinterpret_cast<const float4*>(W);
#pragma unroll
    for (int i = 0; i < (128 * NOUT / 4) / 256; ++i) {
        int id = tid + 256 * i;
        int k = id / (NOUT / 4);
        int col = (id % (NOUT / 4)) * 4;
        float4 v = W4[id];
        *(ushort*)(wt + (col + 0) * 256 + ((k * 2) ^ (((col + 0) & 7) << 4))) = f2bf(v.x);
        *(ushort*)(wt + (col + 1) * 256 + ((k * 2) ^ (((col + 1) & 7) << 4))) = f2bf(v.y);
        *(ushort*)(wt + (col + 2) * 256 + ((k * 2) ^ (((col + 2) & 7) << 4))) = f2bf(v.z);
        *(ushort*)(wt + (col + 3) * 256 + ((k * 2) ^ (((col + 3) & 7) << 4))) = f2bf(v.w);
    }
    // stage X tile: 64 rows x 32 float4 chunks, convert to bf16
#pragma unroll
    for (int i = 0; i < 8; ++i) {
        int id = tid + 256 * i;
        int r = id >> 5, c4 = id & 31;
        int gr = row0 + r;
        float4 v = make_float4(0.f, 0.f, 0.f, 0.f);
        if (gr < N) v = *reinterpret_cast<const float4*>(&X[(size_t)gr * 128 + c4 * 4]);
        uint2 pk;
        pk.x = pack2(v.x, v.y);
        pk.y = pack2(v.z, v.w);
        *reinterpret_cast<uint2*>(xs + r * 256 + ((c4 * 8) ^ ((r & 7) << 4))) = pk;
    }
    __syncthreads();

    const int w = tid >> 6, lane = tid & 63;
    const int rl = w * 16 + (lane & 15);   // A row (local)
    const int kg = lane >> 4;              // k-group 0..3
    f32x4 acc[NOUT / 16];
#pragma unroll
    for (int ct = 0; ct < NOUT / 16; ++ct) acc[ct] = (f32x4){0.f, 0.f, 0.f, 0.f};

#pragma unroll
    for (int ks = 0; ks < 4; ++ks) {
        const int kb = ks * 64 + kg * 16;
        short8 a = *reinterpret_cast<const short8*>(xs + rl * 256 + (kb ^ ((rl & 7) << 4)));
#pragma unroll
        for (int ct = 0; ct < NOUT / 16; ++ct) {
            int col = ct * 16 + (lane & 15);
            short8 bfr = *reinterpret_cast<const short8*>(wt + col * 256 + (kb ^ ((col & 7) << 4)));
            acc[ct] = __builtin_amdgcn_mfma_f32_16x16x32_bf16(a, bfr, acc[ct], 0, 0, 0);
        }
    }
    // C/D layout: col=lane&15, row=(lane>>4)*4+reg (m89-verified)
#pragma unroll
    for (int ct = 0; ct < NOUT / 16; ++ct) {
        int col = ct * 16 + (lane & 15);
#pragma unroll
        for (int r = 0; r < 4; ++r) {
            int gr = row0 + w * 16 + (lane >> 4) * 4 + r;
            if (gr < N) H[(size_t)gr * NOUT + col] = f2bf(acc[ct][r]);
        }
    }
}

// ---------------- hist body: 4 edges/thread ----------------
static __device__ __forceinline__ void hist_body(const int* __restrict__ dst,
                                                 const float* __restrict__ ew,
                                                 float* __restrict__ deg,
                                                 int* __restrict__ cnt,
                                                 int bid, int tid) {
    int i = bid * 256 + tid;
    int e0 = i * 4;
    if (e0 < NE) {
        int4 d4 = *reinterpret_cast<const int4*>(&dst[e0]);
        float4 w4 = *reinterpret_cast<const float4*>(&ew[e0]);
        atomicAdd(&deg[d4.x], w4.x); atomicAdd(&cnt[d4.x], 1);
        atomicAdd(&deg[d4.y], w4.y); atomicAdd(&cnt[d4.y], 1);
        atomicAdd(&deg[d4.z], w4.z); atomicAdd(&cnt[d4.z], 1);
        atomicAdd(&deg[d4.w], w4.w); atomicAdd(&cnt[d4.w], 1);
    }
}

// ---------------- merged: gemm1 blocks + deg_hist blocks ----------------
__global__ __launch_bounds__(256) void k_gemm1_hist(const float* __restrict__ X,
                                                    const float* __restrict__ W1,
                                                    ushort* __restrict__ H, int N,
                                                    const int* __restrict__ dst,
                                                    const float* __restrict__ ew,
                                                    float* __restrict__ deg,
                                                    int* __restrict__ cnt) {
    __shared__ char smem[64 * 256 + 128 * 256];
    if (blockIdx.x < GB1)
        gemm_body<128>(X, W1, H, N, blockIdx.x, threadIdx.x, smem);
    else
        hist_body(dst, ew, deg, cnt, blockIdx.x - GB1, threadIdx.x);
}

// ---------------- standalone GEMMs (layers 2, 3) ----------------
template <int NOUT>
__global__ __launch_bounds__(256) void k_gemm_mfma(const float* __restrict__ X,
                                                   const float* __restrict__ W,
                                                   ushort* __restrict__ H, int N) {
    __shared__ char smem[64 * 256 + NOUT * 256];
    gemm_body<NOUT>(X, W, H, N, blockIdx.x, threadIdx.x, smem);
}

// ---------------- exclusive scan over cnt[0..n) -> rp ----------------

__global__ void k_scan1(const int* __restrict__ cnt, int* __restrict__ rp,
                        int* __restrict__ bsum, int n) {
    __shared__ int tsum[256];
    const int base = blockIdx.x * 1024;
    const int t = threadIdx.x;
    int v[4], s = 0;
#pragma unroll
    for (int j = 0; j < 4; ++j) {
        int idx = base + t * 4 + j;
        v[j] = (idx < n) ? cnt[idx] : 0;
        s += v[j];
    }
    tsum[t] = s;
    __syncthreads();
    for (int off = 1; off < 256; off <<= 1) {
        int x = (t >= off) ? tsum[t - off] : 0;
        __syncthreads();
        tsum[t] += x;
        __syncthreads();
    }
    int excl = (t > 0) ? tsum[t - 1] : 0;
#pragma unroll
    for (int j = 0; j < 4; ++j) {
        int idx = base + t * 4 + j;
        if (idx < n) rp[idx] = excl;
        excl += v[j];
    }
    if (t == 255) bsum[blockIdx.x] = tsum[255];
}

__global__ void k_scan2(int* __restrict__ bsum, int nb) {
    __shared__ int sh[256];
    int t = threadIdx.x;
    sh[t] = (t < nb) ? bsum[t] : 0;
    __syncthreads();
    for (int off = 1; off < 256; off <<= 1) {
        int x = (t >= off) ? sh[t - off] : 0;
        __syncthreads();
        sh[t] += x;
        __syncthreads();
    }
    if (t < nb) bsum[t] = (t > 0) ? sh[t - 1] : 0;
}

// adds block offsets; initializes cursor = rp; computes dinv in place (fused)
__global__ void k_scan3(int* __restrict__ rp, const int* __restrict__ bsum,
                        int* __restrict__ cursor, float* __restrict__ deg, int n) {
    int i = blockIdx.x * blockDim.x + threadIdx.x;
    if (i < n) {
        int v = rp[i] + bsum[i >> 10];
        rp[i] = v;
        cursor[i] = v;
        float d = deg[i];
        deg[i] = (d > 0.f) ? rsqrtf(d) : 0.f;
    }
    if (i == 0) rp[n] = NE;
}

// ---------------- fill CSR buckets: ep[pos] = (src, norm) ----------------
__global__ void k_fill(const int* __restrict__ src, const int* __restrict__ dst,
                       const float* __restrict__ ew, const float* __restrict__ dinv,
                       int* __restrict__ cursor, uint2* __restrict__ ep, int E) {
    int e = blockIdx.x * blockDim.x + threadIdx.x;
    if (e < E) {
        int s = src[e], d = dst[e];
        int pos = atomicAdd(&cursor[d], 1);
        float nv = dinv[s] * ew[e] * dinv[d];
        ep[pos] = make_uint2((uint32)s, __float_as_uint(nv));
    }
}

// ---------------- aggregate (D=128): 4 edge-slots x 16 lanes + ep prefetch ----------------
template <int WAVES, int RELU>
__global__ void k_agg128(const int* __restrict__ rp, const uint2* __restrict__ ep,
                         const ushort* __restrict__ H, const float* __restrict__ b,
                         float* __restrict__ out, int N) {
    const int wave = threadIdx.x >> 6;
    const int lane = threadIdx.x & 63;
    const int n = blockIdx.x * WAVES + wave;
    if (n >= N) return;
    const int e0 = rp[n], e1 = rp[n + 1];
    const int slot = lane >> 4;   // 0..3
    const int l16 = lane & 15;    // feats l16*8 .. +7

    const float4 b0 = *reinterpret_cast<const float4*>(&b[l16 * 8]);
    const float4 b1 = *reinterpret_cast<const float4*>(&b[l16 * 8 + 4]);

    float a[8] = {};
    int e = e0 + slot;
    if (e < e1) {
        uint2 p = ep[e];
        for (;;) {
            const int en = e + 4;
            uint2 pn = ep[en];   // prefetch; may read past e1 (allocated ws), never used
            float w = __uint_as_float(p.y);
            uint4 hv = *reinterpret_cast<const uint4*>(&H[(size_t)p.x * 128 + l16 * 8]);
            a[0] = fmaf(w, bf2f(hv.x & 0xffffu), a[0]);
            a[1] = fmaf(w, bf2f(hv.x >> 16), a[1]);
            a[2] = fmaf(w, bf2f(hv.y & 0xffffu), a[2]);
            a[3] = fmaf(w, bf2f(hv.y >> 16), a[3]);
            a[4] = fmaf(w, bf2f(hv.z & 0xffffu), a[4]);
            a[5] = fmaf(w, bf2f(hv.z >> 16), a[5]);
            a[6] = fmaf(w, bf2f(hv.w & 0xffffu), a[6]);
            a[7] = fmaf(w, bf2f(hv.w >> 16), a[7]);
            e = en;
            if (e >= e1) break;
            p = pn;
        }
    }
#pragma unroll
    for (int j = 0; j < 8; ++j) {
        a[j] += __shfl_xor(a[j], 32);
        a[j] += __shfl_xor(a[j], 16);
    }
    if (lane < 16) {
        float4 o0 = make_float4(a[0] + b0.x, a[1] + b0.y, a[2] + b0.z, a[3] + b0.w);
        float4 o1 = make_float4(a[4] + b1.x, a[5] + b1.y, a[6] + b1.z, a[7] + b1.w);
        if (RELU) {
            o0.x = fmaxf(o0.x, 0.f); o0.y = fmaxf(o0.y, 0.f);
            o0.z = fmaxf(o0.z, 0.f); o0.w = fmaxf(o0.w, 0.f);
            o1.x = fmaxf(o1.x, 0.f); o1.y = fmaxf(o1.y, 0.f);
            o1.z = fmaxf(o1.z, 0.f); o1.w = fmaxf(o1.w, 0.f);
        }
        float* op = &out[(size_t)n * 128 + l16 * 8];
        *reinterpret_cast<float4*>(op) = o0;
        *reinterpret_cast<float4*>(op + 4) = o1;
    }
}

// ---------------- aggregate (D=64): 8 edge-slots x 8 lanes + ep prefetch ----------------
template <int WAVES, int RELU>
__global__ void k_agg64(const int* __restrict__ rp, const uint2* __restrict__ ep,
                        const ushort* __restrict__ H, const float* __restrict__ b,
                        float* __restrict__ out, int N) {
    const int wave = threadIdx.x >> 6;
    const int lane = threadIdx.x & 63;
    const int n = blockIdx.x * WAVES + wave;
    if (n >= N) return;
    const int e0 = rp[n], e1 = rp[n + 1];
    const int slot = lane >> 3;   // 0..7
    const int l8 = lane & 7;      // feats l8*8 .. +7

    const float4 b0 = *reinterpret_cast<const float4*>(&b[l8 * 8]);
    const float4 b1 = *reinterpret_cast<const float4*>(&b[l8 * 8 + 4]);

    float a[8] = {};
    int e = e0 + slot;
    if (e < e1) {
        uint2 p = ep[e];
        for (;;) {
            const int en = e + 8;
            uint2 pn = ep[en];   // prefetch; may read past e1 (allocated ws), never used
            float w = __uint_as_float(p.y);
            uint4 hv = *reinterpret_cast<const uint4*>(&H[(size_t)p.x * 64 + l8 * 8]);
            a[0] = fmaf(w, bf2f(hv.x & 0xffffu), a[0]);
            a[1] = fmaf(w, bf2f(hv.x >> 16), a[1]);
            a[2] = fmaf(w, bf2f(hv.y & 0xffffu), a[2]);
            a[3] = fmaf(w, bf2f(hv.y >> 16), a[3]);
            a[4] = fmaf(w, bf2f(hv.z & 0xffffu), a[4]);
            a[5] = fmaf(w, bf2f(hv.z >> 16), a[5]);
            a[6] = fmaf(w, bf2f(hv.w & 0xffffu), a[6]);
            a[7] = fmaf(w, bf2f(hv.w >> 16), a[7]);
            e = en;
            if (e >= e1) break;
            p = pn;
        }
    }
#pragma unroll
    for (int j = 0; j < 8; ++j) {
        a[j] += __shfl_xor(a[j], 8);
        a[j] += __shfl_xor(a[j], 16);
        a[j] += __shfl_xor(a[j], 32);
    }
    if (lane < 8) {
        float4 o0 = make_float4(a[0] + b0.x, a[1] + b0.y, a[2] + b0.z, a[3] + b0.w);
        float4 o1 = make_float4(a[4] + b1.x, a[5] + b1.y, a[6] + b1.z, a[7] + b1.w);
        if (RELU) {
            o0.x = fmaxf(o0.x, 0.f); o0.y = fmaxf(o0.y, 0.f);
            o0.z = fmaxf(o0.z, 0.f); o0.w = fmaxf(o0.w, 0.f);
            o1.x = fmaxf(o1.x, 0.f); o1.y = fmaxf(o1.y, 0.f);
            o1.z = fmaxf(o1.z, 0.f); o1.w = fmaxf(o1.w, 0.f);
        }
        float* op = &out[(size_t)n * 64 + l8 * 8];
        *reinterpret_cast<float4*>(op) = o0;
        *reinterpret_cast<float4*>(op + 4) = o1;
    }
}

// ---------------- launch ----------------

extern "C" void kernel_launch(void* const* d_in, const int* in_sizes, int n_in,
                              void* d_out, int out_size, void* d_ws, size_t ws_size,
                              hipStream_t stream) {
    const float* x  = (const float*)d_in[0];
    const int*   ei = (const int*)d_in[1];
    const float* ew = (const float*)d_in[2];
    const float* W1 = (const float*)d_in[3];
    const float* b1 = (const float*)d_in[4];
    const float* W2 = (const float*)d_in[5];
    const float* b2 = (const float*)d_in[6];
    const float* W3 = (const float*)d_in[7];
    const float* b3 = (const float*)d_in[8];

    const int* src = ei;
    const int* dst = ei + NE;

    // ws layout
    float*  ws    = (float*)d_ws;
    float*  deg   = ws;                          // NN f (becomes dinv)
    int*    cnt   = (int*)(ws + NN);             // NN i (histogram -> cursor)
    int*    rp    = (int*)(ws + 2 * NN);         // NN+1 i
    int*    bsum  = (int*)(ws + 3 * NN + 64);    // 128 i
    uint2*  ep    = (uint2*)(ws + 3 * NN + 256); // NE uint2 (src, norm)
    ushort* h1    = (ushort*)(ws + 3 * NN + 256 + 2 * NE); // NN*128 bf16
    ushort* h2    = h1 + (size_t)NN * 128;                 // NN*128 bf16
    ushort* h3    = h1;                                    // NN*64 bf16 (aliases h1)

    float* out0 = (float*)d_out;                 // [NN,128]
    float* out1 = out0 + NN * 128;               // [NN,128]
    float* out2 = out1 + NN * 128;               // [NN,64]

    const int B = 256;
    const int NB_SCAN = (NN + 1023) / 1024;      // 98

    // zero deg+cnt (adjacent)
    hipMemsetAsync(deg, 0, 2 * NN * sizeof(float), stream);

    // merged: layer-1 GEMM (independent) overlapped with degree histogram
    k_gemm1_hist<<<GB1 + HB1, 256, 0, stream>>>(x, W1, h1, NN, dst, ew, deg, cnt);

    k_scan1<<<NB_SCAN, 256, 0, stream>>>(cnt, rp, bsum, NN);
    k_scan2<<<1, 256, 0, stream>>>(bsum, NB_SCAN);
    k_scan3<<<(NN + B - 1) / B, B, 0, stream>>>(rp, bsum, cnt, deg, NN);
    k_fill<<<(NE + B - 1) / B, B, 0, stream>>>(src, dst, ew, deg, cnt, ep, NE);

    // ----- layer 1 aggregate -----
    k_agg128<4, 1><<<(NN + 3) / 4, 256, 0, stream>>>(rp, ep, h1, b1, out0, NN);

    // ----- layer 2 -----
    k_gemm_mfma<128><<<GB1, 256, 0, stream>>>(out0, W2, h2, NN);
    k_agg128<4, 1><<<(NN + 3) / 4, 256, 0, stream>>>(rp, ep, h2, b2, out1, NN);

    // ----- layer 3 -----
    k_gemm_mfma<64><<<GB1, 256, 0, stream>>>(out1, W3, h3, NN);
    k_agg64<4, 0><<<(NN + 3) / 4, 256, 0, stream>>>(rp, ep, h3, b3, out2, NN);
}

// Round 11
// 278.555 us; speedup vs baseline: 1.0407x; 1.0407x over previous
//
#include <hip/hip_runtime.h>

#define NN 100000
#define NE 640000

typedef unsigned int uint32;
typedef __attribute__((ext_vector_type(8))) short short8;
typedef __attribute__((ext_vector_type(4))) float f32x4;

static __device__ __forceinline__ ushort f2bf(float f) {
    uint32 u = __float_as_uint(f);
    u = (u + 0x7fffu + ((u >> 16) & 1u)) >> 16;
    return (ushort)u;
}
static __device__ __forceinline__ float bf2f(uint32 bits16) {
    return __uint_as_float(bits16 << 16);
}
static __device__ __forceinline__ uint32 pack2(float a, float b) {
    return (uint32)f2bf(a) | ((uint32)f2bf(b) << 16);
}

// ---------------- degree + histogram ----------------

__global__ void k_deg_hist(const int* __restrict__ dst, const float* __restrict__ ew,
                           float* __restrict__ deg, int* __restrict__ cnt, int E) {
    int e = blockIdx.x * blockDim.x + threadIdx.x;
    if (e < E) {
        int d = dst[e];
        atomicAdd(&deg[d], ew[e]);
        atomicAdd(&cnt[d], 1);
    }
}

// ---------------- exclusive scan over cnt[0..n) -> rp ----------------

__global__ void k_scan1(const int* __restrict__ cnt, int* __restrict__ rp,
                        int* __restrict__ bsum, int n) {
    __shared__ int tsum[256];
    const int base = blockIdx.x * 1024;
    const int t = threadIdx.x;
    int v[4], s = 0;
#pragma unroll
    for (int j = 0; j < 4; ++j) {
        int idx = base + t * 4 + j;
        v[j] = (idx < n) ? cnt[idx] : 0;
        s += v[j];
    }
    tsum[t] = s;
    __syncthreads();
    for (int off = 1; off < 256; off <<= 1) {
        int x = (t >= off) ? tsum[t - off] : 0;
        __syncthreads();
        tsum[t] += x;
        __syncthreads();
    }
    int excl = (t > 0) ? tsum[t - 1] : 0;
#pragma unroll
    for (int j = 0; j < 4; ++j) {
        int idx = base + t * 4 + j;
        if (idx < n) rp[idx] = excl;
        excl += v[j];
    }
    if (t == 255) bsum[blockIdx.x] = tsum[255];
}

__global__ void k_scan2(int* __restrict__ bsum, int nb) {
    __shared__ int sh[256];
    int t = threadIdx.x;
    sh[t] = (t < nb) ? bsum[t] : 0;
    __syncthreads();
    for (int off = 1; off < 256; off <<= 1) {
        int x = (t >= off) ? sh[t - off] : 0;
        __syncthreads();
        sh[t] += x;
        __syncthreads();
    }
    if (t < nb) bsum[t] = (t > 0) ? sh[t - 1] : 0;
}

// adds block offsets; initializes cursor = rp; computes dinv in place (fused)
__global__ void k_scan3(int* __restrict__ rp, const int* __restrict__ bsum,
                        int* __restrict__ cursor, float* __restrict__ deg, int n) {
    int i = blockIdx.x * blockDim.x + threadIdx.x;
    if (i < n) {
        int v = rp[i] + bsum[i >> 10];
        rp[i] = v;
        cursor[i] = v;
        float d = deg[i];
        deg[i] = (d > 0.f) ? rsqrtf(d) : 0.f;
    }
    if (i == 0) rp[n] = NE;
}

// ---------------- fill CSR buckets: ep[pos] = (src, norm) ----------------
__global__ void k_fill(const int* __restrict__ src, const int* __restrict__ dst,
                       const float* __restrict__ ew, const float* __restrict__ dinv,
                       int* __restrict__ cursor, uint2* __restrict__ ep, int E) {
    int e = blockIdx.x * blockDim.x + threadIdx.x;
    if (e < E) {
        int s = src[e], d = dst[e];
        int pos = atomicAdd(&cursor[d], 1);
        float nv = dinv[s] * ew[e] * dinv[d];
        ep[pos] = make_uint2((uint32)s, __float_as_uint(nv));
    }
}

// ---------------- fused W prep: Wt[col][k] = bf16(W[k][col]) for all 3 ----------------
__global__ void k_prepW_all(const float* __restrict__ W1, const float* __restrict__ W2,
                            const float* __restrict__ W3, ushort* __restrict__ wt1,
                            ushort* __restrict__ wt2, ushort* __restrict__ wt3) {
    int o = blockIdx.x * blockDim.x + threadIdx.x;
    if (o < 16384) {
        int col = o >> 7, k = o & 127;
        wt1[o] = f2bf(W1[k * 128 + col]);
    } else if (o < 32768) {
        int oo = o - 16384;
        int col = oo >> 7, k = oo & 127;
        wt2[oo] = f2bf(W2[k * 128 + col]);
    } else if (o < 40960) {
        int oo = o - 32768;
        int col = oo >> 7, k = oo & 127;
        wt3[oo] = f2bf(W3[k * 64 + col]);
    }
}

// ---------------- MFMA GEMM: H(bf16) = X(f32->bf16) @ Wt(bf16) ----------------
// R5/R9-proven: 256 thr (4 waves), 64 rows x NOUT cols. K=128 fully staged, 1 barrier.
// LDS XOR-swizzle: 16B-block index ^= (row&7) => conflict-free fragment reads.
template <int NOUT>
__global__ __launch_bounds__(256) void k_gemm_mfma(const float* __restrict__ X,
                                                   const ushort* __restrict__ Wt,
                                                   ushort* __restrict__ H, int N) {
    __shared__ char smem[64 * 256 + NOUT * 256];
    char* xs = smem;              // [64 rows][128 k] bf16, swizzled
    char* wt = smem + 64 * 256;   // [NOUT cols][128 k] bf16, swizzled
    const int tid = threadIdx.x;
    const int row0 = blockIdx.x * 64;

    // stage Wt (coalesced uint4 copy of pre-transposed bf16)
    const uint4* Wt4 = reinterpret_cast<const uint4*>(Wt);
#pragma unroll
    for (int i = 0; i < NOUT / 16; ++i) {
        int id = tid + 256 * i;
        int col = id >> 4, c4 = id & 15;
        uint4 v = Wt4[id];
        *reinterpret_cast<uint4*>(wt + col * 256 + ((c4 * 16) ^ ((col & 7) << 4))) = v;
    }
    // stage X tile: 64 rows x 32 float4 chunks, convert to bf16
#pragma unroll
    for (int i = 0; i < 8; ++i) {
        int id = tid + 256 * i;
        int r = id >> 5, c4 = id & 31;
        int gr = row0 + r;
        float4 v = make_float4(0.f, 0.f, 0.f, 0.f);
        if (gr < N) v = *reinterpret_cast<const float4*>(&X[(size_t)gr * 128 + c4 * 4]);
        uint2 pk;
        pk.x = pack2(v.x, v.y);
        pk.y = pack2(v.z, v.w);
        *reinterpret_cast<uint2*>(xs + r * 256 + ((c4 * 8) ^ ((r & 7) << 4))) = pk;
    }
    __syncthreads();

    const int w = tid >> 6, lane = tid & 63;
    const int rl = w * 16 + (lane & 15);   // A row (local)
    const int kg = lane >> 4;              // k-group 0..3
    f32x4 acc[NOUT / 16];
#pragma unroll
    for (int ct = 0; ct < NOUT / 16; ++ct) acc[ct] = (f32x4){0.f, 0.f, 0.f, 0.f};

#pragma unroll
    for (int ks = 0; ks < 4; ++ks) {
        const int kb = ks * 64 + kg * 16;
        short8 a = *reinterpret_cast<const short8*>(xs + rl * 256 + (kb ^ ((rl & 7) << 4)));
#pragma unroll
        for (int ct = 0; ct < NOUT / 16; ++ct) {
            int col = ct * 16 + (lane & 15);
            short8 bfr = *reinterpret_cast<const short8*>(wt + col * 256 + (kb ^ ((col & 7) << 4)));
            acc[ct] = __builtin_amdgcn_mfma_f32_16x16x32_bf16(a, bfr, acc[ct], 0, 0, 0);
        }
    }
    // C/D layout: col=lane&15, row=(lane>>4)*4+reg (m89-verified)
#pragma unroll
    for (int ct = 0; ct < NOUT / 16; ++ct) {
        int col = ct * 16 + (lane & 15);
#pragma unroll
        for (int r = 0; r < 4; ++r) {
            int gr = row0 + w * 16 + (lane >> 4) * 4 + r;
            if (gr < N) H[(size_t)gr * NOUT + col] = f2bf(acc[ct][r]);
        }
    }
}

// ---------------- aggregate (D=128): 4 edge-slots x 16 lanes + ep prefetch ----------------
template <int WAVES, int RELU>
__global__ void k_agg128(const int* __restrict__ rp, const uint2* __restrict__ ep,
                         const ushort* __restrict__ H, const float* __restrict__ b,
                         float* __restrict__ out, int N) {
    const int wave = threadIdx.x >> 6;
    const int lane = threadIdx.x & 63;
    const int n = blockIdx.x * WAVES + wave;
    if (n >= N) return;
    const int e0 = rp[n], e1 = rp[n + 1];
    const int slot = lane >> 4;   // 0..3
    const int l16 = lane & 15;    // feats l16*8 .. +7

    const float4 b0 = *reinterpret_cast<const float4*>(&b[l16 * 8]);
    const float4 b1 = *reinterpret_cast<const float4*>(&b[l16 * 8 + 4]);

    float a[8] = {};
    int e = e0 + slot;
    if (e < e1) {
        uint2 p = ep[e];
        for (;;) {
            const int en = e + 4;
            uint2 pn = ep[en];   // prefetch; may read past e1 (allocated ws), never used
            float w = __uint_as_float(p.y);
            uint4 hv = *reinterpret_cast<const uint4*>(&H[(size_t)p.x * 128 + l16 * 8]);
            a[0] = fmaf(w, bf2f(hv.x & 0xffffu), a[0]);
            a[1] = fmaf(w, bf2f(hv.x >> 16), a[1]);
            a[2] = fmaf(w, bf2f(hv.y & 0xffffu), a[2]);
            a[3] = fmaf(w, bf2f(hv.y >> 16), a[3]);
            a[4] = fmaf(w, bf2f(hv.z & 0xffffu), a[4]);
            a[5] = fmaf(w, bf2f(hv.z >> 16), a[5]);
            a[6] = fmaf(w, bf2f(hv.w & 0xffffu), a[6]);
            a[7] = fmaf(w, bf2f(hv.w >> 16), a[7]);
            e = en;
            if (e >= e1) break;
            p = pn;
        }
    }
#pragma unroll
    for (int j = 0; j < 8; ++j) {
        a[j] += __shfl_xor(a[j], 32);
        a[j] += __shfl_xor(a[j], 16);
    }
    if (lane < 16) {
        float4 o0 = make_float4(a[0] + b0.x, a[1] + b0.y, a[2] + b0.z, a[3] + b0.w);
        float4 o1 = make_float4(a[4] + b1.x, a[5] + b1.y, a[6] + b1.z, a[7] + b1.w);
        if (RELU) {
            o0.x = fmaxf(o0.x, 0.f); o0.y = fmaxf(o0.y, 0.f);
            o0.z = fmaxf(o0.z, 0.f); o0.w = fmaxf(o0.w, 0.f);
            o1.x = fmaxf(o1.x, 0.f); o1.y = fmaxf(o1.y, 0.f);
            o1.z = fmaxf(o1.z, 0.f); o1.w = fmaxf(o1.w, 0.f);
        }
        float* op = &out[(size_t)n * 128 + l16 * 8];
        *reinterpret_cast<float4*>(op) = o0;
        *reinterpret_cast<float4*>(op + 4) = o1;
    }
}

// ---------------- aggregate (D=64): 8 edge-slots x 8 lanes + ep prefetch ----------------
template <int WAVES, int RELU>
__global__ void k_agg64(const int* __restrict__ rp, const uint2* __restrict__ ep,
                        const ushort* __restrict__ H, const float* __restrict__ b,
                        float* __restrict__ out, int N) {
    const int wave = threadIdx.x >> 6;
    const int lane = threadIdx.x & 63;
    const int n = blockIdx.x * WAVES + wave;
    if (n >= N) return;
    const int e0 = rp[n], e1 = rp[n + 1];
    const int slot = lane >> 3;   // 0..7
    const int l8 = lane & 7;      // feats l8*8 .. +7

    const float4 b0 = *reinterpret_cast<const float4*>(&b[l8 * 8]);
    const float4 b1 = *reinterpret_cast<const float4*>(&b[l8 * 8 + 4]);

    float a[8] = {};
    int e = e0 + slot;
    if (e < e1) {
        uint2 p = ep[e];
        for (;;) {
            const int en = e + 8;
            uint2 pn = ep[en];   // prefetch; may read past e1 (allocated ws), never used
            float w = __uint_as_float(p.y);
            uint4 hv = *reinterpret_cast<const uint4*>(&H[(size_t)p.x * 64 + l8 * 8]);
            a[0] = fmaf(w, bf2f(hv.x & 0xffffu), a[0]);
            a[1] = fmaf(w, bf2f(hv.x >> 16), a[1]);
            a[2] = fmaf(w, bf2f(hv.y & 0xffffu), a[2]);
            a[3] = fmaf(w, bf2f(hv.y >> 16), a[3]);
            a[4] = fmaf(w, bf2f(hv.z & 0xffffu), a[4]);
            a[5] = fmaf(w, bf2f(hv.z >> 16), a[5]);
            a[6] = fmaf(w, bf2f(hv.w & 0xffffu), a[6]);
            a[7] = fmaf(w, bf2f(hv.w >> 16), a[7]);
            e = en;
            if (e >= e1) break;
            p = pn;
        }
    }
#pragma unroll
    for (int j = 0; j < 8; ++j) {
        a[j] += __shfl_xor(a[j], 8);
        a[j] += __shfl_xor(a[j], 16);
        a[j] += __shfl_xor(a[j], 32);
    }
    if (lane < 8) {
        float4 o0 = make_float4(a[0] + b0.x, a[1] + b0.y, a[2] + b0.z, a[3] + b0.w);
        float4 o1 = make_float4(a[4] + b1.x, a[5] + b1.y, a[6] + b1.z, a[7] + b1.w);
        if (RELU) {
            o0.x = fmaxf(o0.x, 0.f); o0.y = fmaxf(o0.y, 0.f);
            o0.z = fmaxf(o0.z, 0.f); o0.w = fmaxf(o0.w, 0.f);
            o1.x = fmaxf(o1.x, 0.f); o1.y = fmaxf(o1.y, 0.f);
            o1.z = fmaxf(o1.z, 0.f); o1.w = fmaxf(o1.w, 0.f);
        }
        float* op = &out[(size_t)n * 64 + l8 * 8];
        *reinterpret_cast<float4*>(op) = o0;
        *reinterpret_cast<float4*>(op + 4) = o1;
    }
}

// ---------------- launch ----------------

extern "C" void kernel_launch(void* const* d_in, const int* in_sizes, int n_in,
                              void* d_out, int out_size, void* d_ws, size_t ws_size,
                              hipStream_t stream) {
    const float* x  = (const float*)d_in[0];
    const int*   ei = (const int*)d_in[1];
    const float* ew = (const float*)d_in[2];
    const float* W1 = (const float*)d_in[3];
    const float* b1 = (const float*)d_in[4];
    const float* W2 = (const float*)d_in[5];
    const float* b2 = (const float*)d_in[6];
    const float* W3 = (const float*)d_in[7];
    const float* b3 = (const float*)d_in[8];

    const int* src = ei;
    const int* dst = ei + NE;

    // ws layout
    float*  ws    = (float*)d_ws;
    float*  deg   = ws;                          // NN f (becomes dinv)
    int*    cnt   = (int*)(ws + NN);             // NN i (histogram -> cursor)
    int*    rp    = (int*)(ws + 2 * NN);         // NN+1 i
    int*    bsum  = (int*)(ws + 3 * NN + 64);    // 128 i
    uint2*  ep    = (uint2*)(ws + 3 * NN + 256); // NE uint2 (src, norm)
    ushort* h1    = (ushort*)(ws + 3 * NN + 256 + 2 * NE); // NN*128 bf16
    ushort* h2    = h1 + (size_t)NN * 128;                 // NN*128 bf16
    ushort* h3    = h1;                                    // NN*64 bf16 (aliases h1)
    ushort* wt1   = h2 + (size_t)NN * 128;       // 128*128 bf16 (W1^T)
    ushort* wt2   = wt1 + 128 * 128;             // 128*128 bf16
    ushort* wt3   = wt2 + 128 * 128;             // 64*128 bf16

    float* out0 = (float*)d_out;                 // [NN,128]
    float* out1 = out0 + NN * 128;               // [NN,128]
    float* out2 = out1 + NN * 128;               // [NN,64]

    const int B = 256;
    const int NB_SCAN = (NN + 1023) / 1024;      // 98

    // weight prep (one fused kernel)
    k_prepW_all<<<(40960 + B - 1) / B, B, 0, stream>>>(W1, W2, W3, wt1, wt2, wt3);

    // CSR build (deg and cnt adjacent -> one memset)
    hipMemsetAsync(deg, 0, 2 * NN * sizeof(float), stream);
    k_deg_hist<<<(NE + B - 1) / B, B, 0, stream>>>(dst, ew, deg, cnt, NE);
    k_scan1<<<NB_SCAN, 256, 0, stream>>>(cnt, rp, bsum, NN);
    k_scan2<<<1, 256, 0, stream>>>(bsum, NB_SCAN);
    k_scan3<<<(NN + B - 1) / B, B, 0, stream>>>(rp, bsum, cnt, deg, NN);
    k_fill<<<(NE + B - 1) / B, B, 0, stream>>>(src, dst, ew, deg, cnt, ep, NE);

    const int GB = (NN + 63) / 64;               // 1563

    // ----- layer 1 -----
    k_gemm_mfma<128><<<GB, 256, 0, stream>>>(x, wt1, h1, NN);
    k_agg128<4, 1><<<(NN + 3) / 4, 256, 0, stream>>>(rp, ep, h1, b1, out0, NN);

    // ----- layer 2 -----
    k_gemm_mfma<128><<<GB, 256, 0, stream>>>(out0, wt2, h2, NN);
    k_agg128<4, 1><<<(NN + 3) / 4, 256, 0, stream>>>(rp, ep, h2, b2, out1, NN);

    // ----- layer 3 -----
    k_gemm_mfma<64><<<GB, 256, 0, stream>>>(out1, wt3, h3, NN);
    k_agg64<4, 0><<<(NN + 3) / 4, 256, 0, stream>>>(rp, ep, h3, b3, out2, NN);
}

// Round 12
// 272.608 us; speedup vs baseline: 1.0634x; 1.0218x over previous
//
#include <hip/hip_runtime.h>

#define NN 100000
#define NE 640000
#define GB1 ((NN + 63) / 64)   // 1563 gemm blocks (64 rows each)
#define HB1 (NE / 4 / 256)     // 625 hist blocks (4 edges/thread)
#define PWB 160                // prepW blocks (40960 elems / 256)
#define ZB  ((2 * NN + 255) / 256)  // 782 zero blocks

typedef unsigned int uint32;
typedef __attribute__((ext_vector_type(8))) short short8;
typedef __attribute__((ext_vector_type(4))) float f32x4;

static __device__ __forceinline__ ushort f2bf(float f) {
    uint32 u = __float_as_uint(f);
    u = (u + 0x7fffu + ((u >> 16) & 1u)) >> 16;
    return (ushort)u;
}
static __device__ __forceinline__ float bf2f(uint32 bits16) {
    return __uint_as_float(bits16 << 16);
}
static __device__ __forceinline__ uint32 pack2(float a, float b) {
    return (uint32)f2bf(a) | ((uint32)f2bf(b) << 16);
}

// ---------------- prepW (blocks 0..159) + zero deg/cnt (blocks 160+) ----------------
__global__ void k_prep_zero(const float* __restrict__ W1, const float* __restrict__ W2,
                            const float* __restrict__ W3, ushort* __restrict__ wt1,
                            ushort* __restrict__ wt2, ushort* __restrict__ wt3,
                            int* __restrict__ degcnt) {
    const int b = blockIdx.x;
    if (b < PWB) {
        int o = b * 256 + threadIdx.x;
        if (o < 16384) {
            int col = o >> 7, k = o & 127;
            wt1[o] = f2bf(W1[k * 128 + col]);
        } else if (o < 32768) {
            int oo = o - 16384;
            int col = oo >> 7, k = oo & 127;
            wt2[oo] = f2bf(W2[k * 128 + col]);
        } else if (o < 40960) {
            int oo = o - 32768;
            int col = oo >> 7, k = oo & 127;
            wt3[oo] = f2bf(W3[k * 64 + col]);
        }
    } else {
        int i = (b - PWB) * 256 + threadIdx.x;
        if (i < 2 * NN) degcnt[i] = 0;
    }
}

// ---------------- GEMM body (R11-proven): H(bf16) = X(f32->bf16) @ Wt(bf16) ----------------
// 256 thr (4 waves), 64 rows x NOUT cols. K=128 fully staged, 1 barrier.
// LDS XOR-swizzle: 16B-block index ^= (row&7) => conflict-free fragment reads.
template <int NOUT>
static __device__ __forceinline__ void gemm_body(const float* __restrict__ X,
                                                 const ushort* __restrict__ Wt,
                                                 ushort* __restrict__ H, int N,
                                                 int bid, int tid, char* smem) {
    char* xs = smem;              // [64 rows][128 k] bf16, swizzled
    char* wt = smem + 64 * 256;   // [NOUT cols][128 k] bf16, swizzled
    const int row0 = bid * 64;

    // stage Wt (coalesced uint4 copy of pre-transposed bf16)
    const uint4* Wt4 = reinterpret_cast<const uint4*>(Wt);
#pragma unroll
    for (int i = 0; i < NOUT / 16; ++i) {
        int id = tid + 256 * i;
        int col = id >> 4, c4 = id & 15;
        uint4 v = Wt4[id];
        *reinterpret_cast<uint4*>(wt + col * 256 + ((c4 * 16) ^ ((col & 7) << 4))) = v;
    }
    // stage X tile: 64 rows x 32 float4 chunks, convert to bf16
#pragma unroll
    for (int i = 0; i < 8; ++i) {
        int id = tid + 256 * i;
        int r = id >> 5, c4 = id & 31;
        int gr = row0 + r;
        float4 v = make_float4(0.f, 0.f, 0.f, 0.f);
        if (gr < N) v = *reinterpret_cast<const float4*>(&X[(size_t)gr * 128 + c4 * 4]);
        uint2 pk;
        pk.x = pack2(v.x, v.y);
        pk.y = pack2(v.z, v.w);
        *reinterpret_cast<uint2*>(xs + r * 256 + ((c4 * 8) ^ ((r & 7) << 4))) = pk;
    }
    __syncthreads();

    const int w = tid >> 6, lane = tid & 63;
    const int rl = w * 16 + (lane & 15);   // A row (local)
    const int kg = lane >> 4;              // k-group 0..3
    f32x4 acc[NOUT / 16];
#pragma unroll
    for (int ct = 0; ct < NOUT / 16; ++ct) acc[ct] = (f32x4){0.f, 0.f, 0.f, 0.f};

#pragma unroll
    for (int ks = 0; ks < 4; ++ks) {
        const int kb = ks * 64 + kg * 16;
        short8 a = *reinterpret_cast<const short8*>(xs + rl * 256 + (kb ^ ((rl & 7) << 4)));
#pragma unroll
        for (int ct = 0; ct < NOUT / 16; ++ct) {
            int col = ct * 16 + (lane & 15);
            short8 bfr = *reinterpret_cast<const short8*>(wt + col * 256 + (kb ^ ((col & 7) << 4)));
            acc[ct] = __builtin_amdgcn_mfma_f32_16x16x32_bf16(a, bfr, acc[ct], 0, 0, 0);
        }
    }
    // C/D layout: col=lane&15, row=(lane>>4)*4+reg (m89-verified)
#pragma unroll
    for (int ct = 0; ct < NOUT / 16; ++ct) {
        int col = ct * 16 + (lane & 15);
#pragma unroll
        for (int r = 0; r < 4; ++r) {
            int gr = row0 + w * 16 + (lane >> 4) * 4 + r;
            if (gr < N) H[(size_t)gr * NOUT + col] = f2bf(acc[ct][r]);
        }
    }
}

// ---------------- merged: gemm1 blocks + vectorized deg/cnt histogram blocks ----------------
__global__ __launch_bounds__(256) void k_gemm1_hist(const float* __restrict__ X,
                                                    const ushort* __restrict__ Wt1,
                                                    ushort* __restrict__ H, int N,
                                                    const int* __restrict__ dst,
                                                    const float* __restrict__ ew,
                                                    float* __restrict__ deg,
                                                    int* __restrict__ cnt) {
    __shared__ char smem[64 * 256 + 128 * 256];
    if (blockIdx.x < GB1) {
        gemm_body<128>(X, Wt1, H, N, blockIdx.x, threadIdx.x, smem);
    } else {
        int e0 = ((blockIdx.x - GB1) * 256 + threadIdx.x) * 4;
        if (e0 < NE) {
            int4 d4 = *reinterpret_cast<const int4*>(&dst[e0]);
            float4 w4 = *reinterpret_cast<const float4*>(&ew[e0]);
            atomicAdd(&deg[d4.x], w4.x); atomicAdd(&cnt[d4.x], 1);
            atomicAdd(&deg[d4.y], w4.y); atomicAdd(&cnt[d4.y], 1);
            atomicAdd(&deg[d4.z], w4.z); atomicAdd(&cnt[d4.z], 1);
            atomicAdd(&deg[d4.w], w4.w); atomicAdd(&cnt[d4.w], 1);
        }
    }
}

// ---------------- standalone GEMMs (layers 2, 3) ----------------
template <int NOUT>
__global__ __launch_bounds__(256) void k_gemm_mfma(const float* __restrict__ X,
                                                   const ushort* __restrict__ Wt,
                                                   ushort* __restrict__ H, int N) {
    __shared__ char smem[64 * 256 + NOUT * 256];
    gemm_body<NOUT>(X, Wt, H, N, blockIdx.x, threadIdx.x, smem);
}

// ---------------- exclusive scan over cnt[0..n) -> rp ----------------

__global__ void k_scan1(const int* __restrict__ cnt, int* __restrict__ rp,
                        int* __restrict__ bsum, int n) {
    __shared__ int tsum[256];
    const int base = blockIdx.x * 1024;
    const int t = threadIdx.x;
    int v[4], s = 0;
#pragma unroll
    for (int j = 0; j < 4; ++j) {
        int idx = base + t * 4 + j;
        v[j] = (idx < n) ? cnt[idx] : 0;
        s += v[j];
    }
    tsum[t] = s;
    __syncthreads();
    for (int off = 1; off < 256; off <<= 1) {
        int x = (t >= off) ? tsum[t - off] : 0;
        __syncthreads();
        tsum[t] += x;
        __syncthreads();
    }
    int excl = (t > 0) ? tsum[t - 1] : 0;
#pragma unroll
    for (int j = 0; j < 4; ++j) {
        int idx = base + t * 4 + j;
        if (idx < n) rp[idx] = excl;
        excl += v[j];
    }
    if (t == 255) bsum[blockIdx.x] = tsum[255];
}

__global__ void k_scan2(int* __restrict__ bsum, int nb) {
    __shared__ int sh[256];
    int t = threadIdx.x;
    sh[t] = (t < nb) ? bsum[t] : 0;
    __syncthreads();
    for (int off = 1; off < 256; off <<= 1) {
        int x = (t >= off) ? sh[t - off] : 0;
        __syncthreads();
        sh[t] += x;
        __syncthreads();
    }
    if (t < nb) bsum[t] = (t > 0) ? sh[t - 1] : 0;
}

// adds block offsets; initializes cursor = rp; computes dinv in place (fused)
__global__ void k_scan3(int* __restrict__ rp, const int* __restrict__ bsum,
                        int* __restrict__ cursor, float* __restrict__ deg, int n) {
    int i = blockIdx.x * blockDim.x + threadIdx.x;
    if (i < n) {
        int v = rp[i] + bsum[i >> 10];
        rp[i] = v;
        cursor[i] = v;
        float d = deg[i];
        deg[i] = (d > 0.f) ? rsqrtf(d) : 0.f;
    }
    if (i == 0) rp[n] = NE;
}

// ---------------- fill CSR buckets: ep[pos] = (src, norm) ----------------
__global__ void k_fill(const int* __restrict__ src, const int* __restrict__ dst,
                       const float* __restrict__ ew, const float* __restrict__ dinv,
                       int* __restrict__ cursor, uint2* __restrict__ ep, int E) {
    int e = blockIdx.x * blockDim.x + threadIdx.x;
    if (e < E) {
        int s = src[e], d = dst[e];
        int pos = atomicAdd(&cursor[d], 1);
        float nv = dinv[s] * ew[e] * dinv[d];
        ep[pos] = make_uint2((uint32)s, __float_as_uint(nv));
    }
}

// ---------------- aggregate (D=128): 4 edge-slots x 16 lanes + ep prefetch ----------------
template <int WAVES, int RELU>
__global__ void k_agg128(const int* __restrict__ rp, const uint2* __restrict__ ep,
                         const ushort* __restrict__ H, const float* __restrict__ b,
                         float* __restrict__ out, int N) {
    const int wave = threadIdx.x >> 6;
    const int lane = threadIdx.x & 63;
    const int n = blockIdx.x * WAVES + wave;
    if (n >= N) return;
    const int e0 = rp[n], e1 = rp[n + 1];
    const int slot = lane >> 4;   // 0..3
    const int l16 = lane & 15;    // feats l16*8 .. +7

    const float4 b0 = *reinterpret_cast<const float4*>(&b[l16 * 8]);
    const float4 b1 = *reinterpret_cast<const float4*>(&b[l16 * 8 + 4]);

    float a[8] = {};
    int e = e0 + slot;
    if (e < e1) {
        uint2 p = ep[e];
        for (;;) {
            const int en = e + 4;
            uint2 pn = ep[en];   // prefetch; may read past e1 (allocated ws), never used
            float w = __uint_as_float(p.y);
            uint4 hv = *reinterpret_cast<const uint4*>(&H[(size_t)p.x * 128 + l16 * 8]);
            a[0] = fmaf(w, bf2f(hv.x & 0xffffu), a[0]);
            a[1] = fmaf(w, bf2f(hv.x >> 16), a[1]);
            a[2] = fmaf(w, bf2f(hv.y & 0xffffu), a[2]);
            a[3] = fmaf(w, bf2f(hv.y >> 16), a[3]);
            a[4] = fmaf(w, bf2f(hv.z & 0xffffu), a[4]);
            a[5] = fmaf(w, bf2f(hv.z >> 16), a[5]);
            a[6] = fmaf(w, bf2f(hv.w & 0xffffu), a[6]);
            a[7] = fmaf(w, bf2f(hv.w >> 16), a[7]);
            e = en;
            if (e >= e1) break;
            p = pn;
        }
    }
#pragma unroll
    for (int j = 0; j < 8; ++j) {
        a[j] += __shfl_xor(a[j], 32);
        a[j] += __shfl_xor(a[j], 16);
    }
    if (lane < 16) {
        float4 o0 = make_float4(a[0] + b0.x, a[1] + b0.y, a[2] + b0.z, a[3] + b0.w);
        float4 o1 = make_float4(a[4] + b1.x, a[5] + b1.y, a[6] + b1.z, a[7] + b1.w);
        if (RELU) {
            o0.x = fmaxf(o0.x, 0.f); o0.y = fmaxf(o0.y, 0.f);
            o0.z = fmaxf(o0.z, 0.f); o0.w = fmaxf(o0.w, 0.f);
            o1.x = fmaxf(o1.x, 0.f); o1.y = fmaxf(o1.y, 0.f);
            o1.z = fmaxf(o1.z, 0.f); o1.w = fmaxf(o1.w, 0.f);
        }
        float* op = &out[(size_t)n * 128 + l16 * 8];
        *reinterpret_cast<float4*>(op) = o0;
        *reinterpret_cast<float4*>(op + 4) = o1;
    }
}

// ---------------- aggregate (D=64): 8 edge-slots x 8 lanes + ep prefetch ----------------
template <int WAVES, int RELU>
__global__ void k_agg64(const int* __restrict__ rp, const uint2* __restrict__ ep,
                        const ushort* __restrict__ H, const float* __restrict__ b,
                        float* __restrict__ out, int N) {
    const int wave = threadIdx.x >> 6;
    const int lane = threadIdx.x & 63;
    const int n = blockIdx.x * WAVES + wave;
    if (n >= N) return;
    const int e0 = rp[n], e1 = rp[n + 1];
    const int slot = lane >> 3;   // 0..7
    const int l8 = lane & 7;      // feats l8*8 .. +7

    const float4 b0 = *reinterpret_cast<const float4*>(&b[l8 * 8]);
    const float4 b1 = *reinterpret_cast<const float4*>(&b[l8 * 8 + 4]);

    float a[8] = {};
    int e = e0 + slot;
    if (e < e1) {
        uint2 p = ep[e];
        for (;;) {
            const int en = e + 8;
            uint2 pn = ep[en];   // prefetch; may read past e1 (allocated ws), never used
            float w = __uint_as_float(p.y);
            uint4 hv = *reinterpret_cast<const uint4*>(&H[(size_t)p.x * 64 + l8 * 8]);
            a[0] = fmaf(w, bf2f(hv.x & 0xffffu), a[0]);
            a[1] = fmaf(w, bf2f(hv.x >> 16), a[1]);
            a[2] = fmaf(w, bf2f(hv.y & 0xffffu), a[2]);
            a[3] = fmaf(w, bf2f(hv.y >> 16), a[3]);
            a[4] = fmaf(w, bf2f(hv.z & 0xffffu), a[4]);
            a[5] = fmaf(w, bf2f(hv.z >> 16), a[5]);
            a[6] = fmaf(w, bf2f(hv.w & 0xffffu), a[6]);
            a[7] = fmaf(w, bf2f(hv.w >> 16), a[7]);
            e = en;
            if (e >= e1) break;
            p = pn;
        }
    }
#pragma unroll
    for (int j = 0; j < 8; ++j) {
        a[j] += __shfl_xor(a[j], 8);
        a[j] += __shfl_xor(a[j], 16);
        a[j] += __shfl_xor(a[j], 32);
    }
    if (lane < 8) {
        float4 o0 = make_float4(a[0] + b0.x, a[1] + b0.y, a[2] + b0.z, a[3] + b0.w);
        float4 o1 = make_float4(a[4] + b1.x, a[5] + b1.y, a[6] + b1.z, a[7] + b1.w);
        if (RELU) {
            o0.x = fmaxf(o0.x, 0.f); o0.y = fmaxf(o0.y, 0.f);
            o0.z = fmaxf(o0.z, 0.f); o0.w = fmaxf(o0.w, 0.f);
            o1.x = fmaxf(o1.x, 0.f); o1.y = fmaxf(o1.y, 0.f);
            o1.z = fmaxf(o1.z, 0.f); o1.w = fmaxf(o1.w, 0.f);
        }
        float* op = &out[(size_t)n * 64 + l8 * 8];
        *reinterpret_cast<float4*>(op) = o0;
        *reinterpret_cast<float4*>(op + 4) = o1;
    }
}

// ---------------- launch ----------------

extern "C" void kernel_launch(void* const* d_in, const int* in_sizes, int n_in,
                              void* d_out, int out_size, void* d_ws, size_t ws_size,
                              hipStream_t stream) {
    const float* x  = (const float*)d_in[0];
    const int*   ei = (const int*)d_in[1];
    const float* ew = (const float*)d_in[2];
    const float* W1 = (const float*)d_in[3];
    const float* b1 = (const float*)d_in[4];
    const float* W2 = (const float*)d_in[5];
    const float* b2 = (const float*)d_in[6];
    const float* W3 = (const float*)d_in[7];
    const float* b3 = (const float*)d_in[8];

    const int* src = ei;
    const int* dst = ei + NE;

    // ws layout
    float*  ws    = (float*)d_ws;
    float*  deg   = ws;                          // NN f (becomes dinv)
    int*    cnt   = (int*)(ws + NN);             // NN i (histogram -> cursor)
    int*    rp    = (int*)(ws + 2 * NN);         // NN+1 i
    int*    bsum  = (int*)(ws + 3 * NN + 64);    // 128 i
    uint2*  ep    = (uint2*)(ws + 3 * NN + 256); // NE uint2 (src, norm)
    ushort* h1    = (ushort*)(ws + 3 * NN + 256 + 2 * NE); // NN*128 bf16
    ushort* h2    = h1 + (size_t)NN * 128;                 // NN*128 bf16
    ushort* h3    = h1;                                    // NN*64 bf16 (aliases h1)
    ushort* wt1   = h2 + (size_t)NN * 128;       // 128*128 bf16 (W1^T)
    ushort* wt2   = wt1 + 128 * 128;             // 128*128 bf16
    ushort* wt3   = wt2 + 128 * 128;             // 64*128 bf16

    float* out0 = (float*)d_out;                 // [NN,128]
    float* out1 = out0 + NN * 128;               // [NN,128]
    float* out2 = out1 + NN * 128;               // [NN,64]

    const int B = 256;
    const int NB_SCAN = (NN + 1023) / 1024;      // 98

    // prepW + zero deg/cnt (one kernel)
    k_prep_zero<<<PWB + ZB, B, 0, stream>>>(W1, W2, W3, wt1, wt2, wt3, (int*)deg);

    // merged: layer-1 GEMM (clean Wt staging) + degree histogram
    k_gemm1_hist<<<GB1 + HB1, 256, 0, stream>>>(x, wt1, h1, NN, dst, ew, deg, cnt);

    k_scan1<<<NB_SCAN, 256, 0, stream>>>(cnt, rp, bsum, NN);
    k_scan2<<<1, 256, 0, stream>>>(bsum, NB_SCAN);
    k_scan3<<<(NN + B - 1) / B, B, 0, stream>>>(rp, bsum, cnt, deg, NN);
    k_fill<<<(NE + B - 1) / B, B, 0, stream>>>(src, dst, ew, deg, cnt, ep, NE);

    // ----- layer 1 aggregate -----
    k_agg128<4, 1><<<(NN + 3) / 4, 256, 0, stream>>>(rp, ep, h1, b1, out0, NN);

    // ----- layer 2 -----
    k_gemm_mfma<128><<<GB1, 256, 0, stream>>>(out0, wt2, h2, NN);
    k_agg128<4, 1><<<(NN + 3) / 4, 256, 0, stream>>>(rp, ep, h2, b2, out1, NN);

    // ----- layer 3 -----
    k_gemm_mfma<64><<<GB1, 256, 0, stream>>>(out1, wt3, h3, NN);
    k_agg64<4, 0><<<(NN + 3) / 4, 256, 0, stream>>>(rp, ep, h3, b3, out2, NN);
}

// Round 13
// 265.888 us; speedup vs baseline: 1.0903x; 1.0253x over previous
//
#include <hip/hip_runtime.h>

#define NN 100000
#define NE 640000
#define GB1 ((NN + 63) / 64)   // 1563 gemm blocks (64 rows each)
#define HB1 ((NE + 255) / 256) // 2500 hist blocks (1 edge/thread)
#define PWB 160                // prepW blocks (40960 elems / 256)
#define ZB  ((2 * NN + 255) / 256)  // 782 zero blocks

typedef unsigned int uint32;
typedef __attribute__((ext_vector_type(8))) short short8;
typedef __attribute__((ext_vector_type(4))) float f32x4;

static __device__ __forceinline__ ushort f2bf(float f) {
    uint32 u = __float_as_uint(f);
    u = (u + 0x7fffu + ((u >> 16) & 1u)) >> 16;
    return (ushort)u;
}
static __device__ __forceinline__ float bf2f(uint32 bits16) {
    return __uint_as_float(bits16 << 16);
}
static __device__ __forceinline__ uint32 pack2(float a, float b) {
    return (uint32)f2bf(a) | ((uint32)f2bf(b) << 16);
}

// ---------------- prepW (blocks 0..159) + zero deg/cnt (blocks 160+) ----------------
__global__ void k_prep_zero(const float* __restrict__ W1, const float* __restrict__ W2,
                            const float* __restrict__ W3, ushort* __restrict__ wt1,
                            ushort* __restrict__ wt2, ushort* __restrict__ wt3,
                            int* __restrict__ degcnt) {
    const int b = blockIdx.x;
    if (b < PWB) {
        int o = b * 256 + threadIdx.x;
        if (o < 16384) {
            int col = o >> 7, k = o & 127;
            wt1[o] = f2bf(W1[k * 128 + col]);
        } else if (o < 32768) {
            int oo = o - 16384;
            int col = oo >> 7, k = oo & 127;
            wt2[oo] = f2bf(W2[k * 128 + col]);
        } else if (o < 40960) {
            int oo = o - 32768;
            int col = oo >> 7, k = oo & 127;
            wt3[oo] = f2bf(W3[k * 64 + col]);
        }
    } else {
        int i = (b - PWB) * 256 + threadIdx.x;
        if (i < 2 * NN) degcnt[i] = 0;
    }
}

// ---------------- GEMM body (R11-proven): H(bf16) = X(f32->bf16) @ Wt(bf16) ----------------
// 256 thr (4 waves), 64 rows x NOUT cols. K=128 fully staged, 1 barrier.
// LDS XOR-swizzle: 16B-block index ^= (row&7) => conflict-free fragment reads.
template <int NOUT>
static __device__ __forceinline__ void gemm_body(const float* __restrict__ X,
                                                 const ushort* __restrict__ Wt,
                                                 ushort* __restrict__ H, int N,
                                                 int bid, int tid, char* smem) {
    char* xs = smem;              // [64 rows][128 k] bf16, swizzled
    char* wt = smem + 64 * 256;   // [NOUT cols][128 k] bf16, swizzled
    const int row0 = bid * 64;

    // stage Wt (coalesced uint4 copy of pre-transposed bf16)
    const uint4* Wt4 = reinterpret_cast<const uint4*>(Wt);
#pragma unroll
    for (int i = 0; i < NOUT / 16; ++i) {
        int id = tid + 256 * i;
        int col = id >> 4, c4 = id & 15;
        uint4 v = Wt4[id];
        *reinterpret_cast<uint4*>(wt + col * 256 + ((c4 * 16) ^ ((col & 7) << 4))) = v;
    }
    // stage X tile: 64 rows x 32 float4 chunks, convert to bf16
#pragma unroll
    for (int i = 0; i < 8; ++i) {
        int id = tid + 256 * i;
        int r = id >> 5, c4 = id & 31;
        int gr = row0 + r;
        float4 v = make_float4(0.f, 0.f, 0.f, 0.f);
        if (gr < N) v = *reinterpret_cast<const float4*>(&X[(size_t)gr * 128 + c4 * 4]);
        uint2 pk;
        pk.x = pack2(v.x, v.y);
        pk.y = pack2(v.z, v.w);
        *reinterpret_cast<uint2*>(xs + r * 256 + ((c4 * 8) ^ ((r & 7) << 4))) = pk;
    }
    __syncthreads();

    const int w = tid >> 6, lane = tid & 63;
    const int rl = w * 16 + (lane & 15);   // A row (local)
    const int kg = lane >> 4;              // k-group 0..3
    f32x4 acc[NOUT / 16];
#pragma unroll
    for (int ct = 0; ct < NOUT / 16; ++ct) acc[ct] = (f32x4){0.f, 0.f, 0.f, 0.f};

#pragma unroll
    for (int ks = 0; ks < 4; ++ks) {
        const int kb = ks * 64 + kg * 16;
        short8 a = *reinterpret_cast<const short8*>(xs + rl * 256 + (kb ^ ((rl & 7) << 4)));
#pragma unroll
        for (int ct = 0; ct < NOUT / 16; ++ct) {
            int col = ct * 16 + (lane & 15);
            short8 bfr = *reinterpret_cast<const short8*>(wt + col * 256 + (kb ^ ((col & 7) << 4)));
            acc[ct] = __builtin_amdgcn_mfma_f32_16x16x32_bf16(a, bfr, acc[ct], 0, 0, 0);
        }
    }
    // C/D layout: col=lane&15, row=(lane>>4)*4+reg (m89-verified)
#pragma unroll
    for (int ct = 0; ct < NOUT / 16; ++ct) {
        int col = ct * 16 + (lane & 15);
#pragma unroll
        for (int r = 0; r < 4; ++r) {
            int gr = row0 + w * 16 + (lane >> 4) * 4 + r;
            if (gr < N) H[(size_t)gr * NOUT + col] = f2bf(acc[ct][r]);
        }
    }
}

// ---------------- merged: hist blocks (first, 1 edge/thread) + gemm1 blocks ----------------
__global__ __launch_bounds__(256) void k_gemm1_hist(const float* __restrict__ X,
                                                    const ushort* __restrict__ Wt1,
                                                    ushort* __restrict__ H, int N,
                                                    const int* __restrict__ dst,
                                                    const float* __restrict__ ew,
                                                    float* __restrict__ deg,
                                                    int* __restrict__ cnt) {
    __shared__ char smem[64 * 256 + 128 * 256];
    if (blockIdx.x < HB1) {
        int e = blockIdx.x * 256 + threadIdx.x;
        if (e < NE) {
            int d = dst[e];
            atomicAdd(&deg[d], ew[e]);
            atomicAdd(&cnt[d], 1);
        }
    } else {
        gemm_body<128>(X, Wt1, H, N, blockIdx.x - HB1, threadIdx.x, smem);
    }
}

// ---------------- standalone GEMMs (layers 2, 3) ----------------
template <int NOUT>
__global__ __launch_bounds__(256) void k_gemm_mfma(const float* __restrict__ X,
                                                   const ushort* __restrict__ Wt,
                                                   ushort* __restrict__ H, int N) {
    __shared__ char smem[64 * 256 + NOUT * 256];
    gemm_body<NOUT>(X, Wt, H, N, blockIdx.x, threadIdx.x, smem);
}

// ---------------- exclusive scan over cnt[0..n) -> rp ----------------

__global__ void k_scan1(const int* __restrict__ cnt, int* __restrict__ rp,
                        int* __restrict__ bsum, int n) {
    __shared__ int tsum[256];
    const int base = blockIdx.x * 1024;
    const int t = threadIdx.x;
    int v[4], s = 0;
#pragma unroll
    for (int j = 0; j < 4; ++j) {
        int idx = base + t * 4 + j;
        v[j] = (idx < n) ? cnt[idx] : 0;
        s += v[j];
    }
    tsum[t] = s;
    __syncthreads();
    for (int off = 1; off < 256; off <<= 1) {
        int x = (t >= off) ? tsum[t - off] : 0;
        __syncthreads();
        tsum[t] += x;
        __syncthreads();
    }
    int excl = (t > 0) ? tsum[t - 1] : 0;
#pragma unroll
    for (int j = 0; j < 4; ++j) {
        int idx = base + t * 4 + j;
        if (idx < n) rp[idx] = excl;
        excl += v[j];
    }
    if (t == 255) bsum[blockIdx.x] = tsum[255];
}

__global__ void k_scan2(int* __restrict__ bsum, int nb) {
    __shared__ int sh[256];
    int t = threadIdx.x;
    sh[t] = (t < nb) ? bsum[t] : 0;
    __syncthreads();
    for (int off = 1; off < 256; off <<= 1) {
        int x = (t >= off) ? sh[t - off] : 0;
        __syncthreads();
        sh[t] += x;
        __syncthreads();
    }
    if (t < nb) bsum[t] = (t > 0) ? sh[t - 1] : 0;
}

// adds block offsets; initializes cursor = rp; computes dinv in place (fused)
__global__ void k_scan3(int* __restrict__ rp, const int* __restrict__ bsum,
                        int* __restrict__ cursor, float* __restrict__ deg, int n) {
    int i = blockIdx.x * blockDim.x + threadIdx.x;
    if (i < n) {
        int v = rp[i] + bsum[i >> 10];
        rp[i] = v;
        cursor[i] = v;
        float d = deg[i];
        deg[i] = (d > 0.f) ? rsqrtf(d) : 0.f;
    }
    if (i == 0) rp[n] = NE;
}

// ---------------- fill CSR buckets: ep[pos] = (src, norm) ----------------
__global__ void k_fill(const int* __restrict__ src, const int* __restrict__ dst,
                       const float* __restrict__ ew, const float* __restrict__ dinv,
                       int* __restrict__ cursor, uint2* __restrict__ ep, int E) {
    int e = blockIdx.x * blockDim.x + threadIdx.x;
    if (e < E) {
        int s = src[e], d = dst[e];
        int pos = atomicAdd(&cursor[d], 1);
        float nv = dinv[s] * ew[e] * dinv[d];
        ep[pos] = make_uint2((uint32)s, __float_as_uint(nv));
    }
}

// ---------------- aggregate (D=128): 4 edge-slots x 16 lanes + ep prefetch ----------------
template <int WAVES, int RELU>
__global__ void k_agg128(const int* __restrict__ rp, const uint2* __restrict__ ep,
                         const ushort* __restrict__ H, const float* __restrict__ b,
                         float* __restrict__ out, int N) {
    const int wave = threadIdx.x >> 6;
    const int lane = threadIdx.x & 63;
    const int n = blockIdx.x * WAVES + wave;
    if (n >= N) return;
    const int e0 = rp[n], e1 = rp[n + 1];
    const int slot = lane >> 4;   // 0..3
    const int l16 = lane & 15;    // feats l16*8 .. +7

    const float4 b0 = *reinterpret_cast<const float4*>(&b[l16 * 8]);
    const float4 b1 = *reinterpret_cast<const float4*>(&b[l16 * 8 + 4]);

    float a[8] = {};
    int e = e0 + slot;
    if (e < e1) {
        uint2 p = ep[e];
        for (;;) {
            const int en = e + 4;
            uint2 pn = ep[en];   // prefetch; may read past e1 (allocated ws), never used
            float w = __uint_as_float(p.y);
            uint4 hv = *reinterpret_cast<const uint4*>(&H[(size_t)p.x * 128 + l16 * 8]);
            a[0] = fmaf(w, bf2f(hv.x & 0xffffu), a[0]);
            a[1] = fmaf(w, bf2f(hv.x >> 16), a[1]);
            a[2] = fmaf(w, bf2f(hv.y & 0xffffu), a[2]);
            a[3] = fmaf(w, bf2f(hv.y >> 16), a[3]);
            a[4] = fmaf(w, bf2f(hv.z & 0xffffu), a[4]);
            a[5] = fmaf(w, bf2f(hv.z >> 16), a[5]);
            a[6] = fmaf(w, bf2f(hv.w & 0xffffu), a[6]);
            a[7] = fmaf(w, bf2f(hv.w >> 16), a[7]);
            e = en;
            if (e >= e1) break;
            p = pn;
        }
    }
#pragma unroll
    for (int j = 0; j < 8; ++j) {
        a[j] += __shfl_xor(a[j], 32);
        a[j] += __shfl_xor(a[j], 16);
    }
    if (lane < 16) {
        float4 o0 = make_float4(a[0] + b0.x, a[1] + b0.y, a[2] + b0.z, a[3] + b0.w);
        float4 o1 = make_float4(a[4] + b1.x, a[5] + b1.y, a[6] + b1.z, a[7] + b1.w);
        if (RELU) {
            o0.x = fmaxf(o0.x, 0.f); o0.y = fmaxf(o0.y, 0.f);
            o0.z = fmaxf(o0.z, 0.f); o0.w = fmaxf(o0.w, 0.f);
            o1.x = fmaxf(o1.x, 0.f); o1.y = fmaxf(o1.y, 0.f);
            o1.z = fmaxf(o1.z, 0.f); o1.w = fmaxf(o1.w, 0.f);
        }
        float* op = &out[(size_t)n * 128 + l16 * 8];
        *reinterpret_cast<float4*>(op) = o0;
        *reinterpret_cast<float4*>(op + 4) = o1;
    }
}

// ---------------- aggregate (D=64): 8 edge-slots x 8 lanes + ep prefetch ----------------
template <int WAVES, int RELU>
__global__ void k_agg64(const int* __restrict__ rp, const uint2* __restrict__ ep,
                        const ushort* __restrict__ H, const float* __restrict__ b,
                        float* __restrict__ out, int N) {
    const int wave = threadIdx.x >> 6;
    const int lane = threadIdx.x & 63;
    const int n = blockIdx.x * WAVES + wave;
    if (n >= N) return;
    const int e0 = rp[n], e1 = rp[n + 1];
    const int slot = lane >> 3;   // 0..7
    const int l8 = lane & 7;      // feats l8*8 .. +7

    const float4 b0 = *reinterpret_cast<const float4*>(&b[l8 * 8]);
    const float4 b1 = *reinterpret_cast<const float4*>(&b[l8 * 8 + 4]);

    float a[8] = {};
    int e = e0 + slot;
    if (e < e1) {
        uint2 p = ep[e];
        for (;;) {
            const int en = e + 8;
            uint2 pn = ep[en];   // prefetch; may read past e1 (allocated ws), never used
            float w = __uint_as_float(p.y);
            uint4 hv = *reinterpret_cast<const uint4*>(&H[(size_t)p.x * 64 + l8 * 8]);
            a[0] = fmaf(w, bf2f(hv.x & 0xffffu), a[0]);
            a[1] = fmaf(w, bf2f(hv.x >> 16), a[1]);
            a[2] = fmaf(w, bf2f(hv.y & 0xffffu), a[2]);
            a[3] = fmaf(w, bf2f(hv.y >> 16), a[3]);
            a[4] = fmaf(w, bf2f(hv.z & 0xffffu), a[4]);
            a[5] = fmaf(w, bf2f(hv.z >> 16), a[5]);
            a[6] = fmaf(w, bf2f(hv.w & 0xffffu), a[6]);
            a[7] = fmaf(w, bf2f(hv.w >> 16), a[7]);
            e = en;
            if (e >= e1) break;
            p = pn;
        }
    }
#pragma unroll
    for (int j = 0; j < 8; ++j) {
        a[j] += __shfl_xor(a[j], 8);
        a[j] += __shfl_xor(a[j], 16);
        a[j] += __shfl_xor(a[j], 32);
    }
    if (lane < 8) {
        float4 o0 = make_float4(a[0] + b0.x, a[1] + b0.y, a[2] + b0.z, a[3] + b0.w);
        float4 o1 = make_float4(a[4] + b1.x, a[5] + b1.y, a[6] + b1.z, a[7] + b1.w);
        if (RELU) {
            o0.x = fmaxf(o0.x, 0.f); o0.y = fmaxf(o0.y, 0.f);
            o0.z = fmaxf(o0.z, 0.f); o0.w = fmaxf(o0.w, 0.f);
            o1.x = fmaxf(o1.x, 0.f); o1.y = fmaxf(o1.y, 0.f);
            o1.z = fmaxf(o1.z, 0.f); o1.w = fmaxf(o1.w, 0.f);
        }
        float* op = &out[(size_t)n * 64 + l8 * 8];
        *reinterpret_cast<float4*>(op) = o0;
        *reinterpret_cast<float4*>(op + 4) = o1;
    }
}

// ---------------- launch ----------------

extern "C" void kernel_launch(void* const* d_in, const int* in_sizes, int n_in,
                              void* d_out, int out_size, void* d_ws, size_t ws_size,
                              hipStream_t stream) {
    const float* x  = (const float*)d_in[0];
    const int*   ei = (const int*)d_in[1];
    const float* ew = (const float*)d_in[2];
    const float* W1 = (const float*)d_in[3];
    const float* b1 = (const float*)d_in[4];
    const float* W2 = (const float*)d_in[5];
    const float* b2 = (const float*)d_in[6];
    const float* W3 = (const float*)d_in[7];
    const float* b3 = (const float*)d_in[8];

    const int* src = ei;
    const int* dst = ei + NE;

    // ws layout
    float*  ws    = (float*)d_ws;
    float*  deg   = ws;                          // NN f (becomes dinv)
    int*    cnt   = (int*)(ws + NN);             // NN i (histogram -> cursor)
    int*    rp    = (int*)(ws + 2 * NN);         // NN+1 i
    int*    bsum  = (int*)(ws + 3 * NN + 64);    // 128 i
    uint2*  ep    = (uint2*)(ws + 3 * NN + 256); // NE uint2 (src, norm)
    ushort* h1    = (ushort*)(ws + 3 * NN + 256 + 2 * NE); // NN*128 bf16
    ushort* h2    = h1 + (size_t)NN * 128;                 // NN*128 bf16
    ushort* h3    = h1;                                    // NN*64 bf16 (aliases h1)
    ushort* wt1   = h2 + (size_t)NN * 128;       // 128*128 bf16 (W1^T)
    ushort* wt2   = wt1 + 128 * 128;             // 128*128 bf16
    ushort* wt3   = wt2 + 128 * 128;             // 64*128 bf16

    float* out0 = (float*)d_out;                 // [NN,128]
    float* out1 = out0 + NN * 128;               // [NN,128]
    float* out2 = out1 + NN * 128;               // [NN,64]

    const int B = 256;
    const int NB_SCAN = (NN + 1023) / 1024;      // 98

    // prepW + zero deg/cnt (one kernel)
    k_prep_zero<<<PWB + ZB, B, 0, stream>>>(W1, W2, W3, wt1, wt2, wt3, (int*)deg);

    // merged: degree histogram (blocks first, 1 edge/thread) + layer-1 GEMM
    k_gemm1_hist<<<HB1 + GB1, 256, 0, stream>>>(x, wt1, h1, NN, dst, ew, deg, cnt);

    k_scan1<<<NB_SCAN, 256, 0, stream>>>(cnt, rp, bsum, NN);
    k_scan2<<<1, 256, 0, stream>>>(bsum, NB_SCAN);
    k_scan3<<<(NN + B - 1) / B, B, 0, stream>>>(rp, bsum, cnt, deg, NN);
    k_fill<<<(NE + B - 1) / B, B, 0, stream>>>(src, dst, ew, deg, cnt, ep, NE);

    // ----- layer 1 aggregate -----
    k_agg128<4, 1><<<(NN + 3) / 4, 256, 0, stream>>>(rp, ep, h1, b1, out0, NN);

    // ----- layer 2 -----
    k_gemm_mfma<128><<<GB1, 256, 0, stream>>>(out0, wt2, h2, NN);
    k_agg128<4, 1><<<(NN + 3) / 4, 256, 0, stream>>>(rp, ep, h2, b2, out1, NN);

    // ----- layer 3 -----
    k_gemm_mfma<64><<<GB1, 256, 0, stream>>>(out1, wt3, h3, NN);
    k_agg64<4, 0><<<(NN + 3) / 4, 256, 0, stream>>>(rp, ep, h3, b3, out2, NN);
}

// Round 14
// 239.303 us; speedup vs baseline: 1.2114x; 1.1111x over previous
//
#include <hip/hip_runtime.h>

#define NN 100000
#define NE 640000
#define GB1 ((NN + 63) / 64)        // 1563 gemm blocks (64 rows each)
#define EPB ((NE + GB1 - 1) / GB1)  // 410 edges per gemm block (hist tail)
#define PWB 160                     // prepW blocks (40960 elems / 256)
#define ZB  ((2 * NN + 255) / 256)  // 782 zero blocks (NN uint64)

typedef unsigned int uint32;
typedef unsigned long long uint64;
typedef __attribute__((ext_vector_type(8))) short short8;
typedef __attribute__((ext_vector_type(4))) float f32x4;

static __device__ __forceinline__ ushort f2bf(float f) {
    uint32 u = __float_as_uint(f);
    u = (u + 0x7fffu + ((u >> 16) & 1u)) >> 16;
    return (ushort)u;
}
static __device__ __forceinline__ float bf2f(uint32 bits16) {
    return __uint_as_float(bits16 << 16);
}
static __device__ __forceinline__ uint32 pack2(float a, float b) {
    return (uint32)f2bf(a) | ((uint32)f2bf(b) << 16);
}

// ---------------- prepW (blocks 0..159) + zero packed degcnt (blocks 160+) ----------------
__global__ void k_prep_zero(const float* __restrict__ W1, const float* __restrict__ W2,
                            const float* __restrict__ W3, ushort* __restrict__ wt1,
                            ushort* __restrict__ wt2, ushort* __restrict__ wt3,
                            int* __restrict__ degcnt_i) {
    const int b = blockIdx.x;
    if (b < PWB) {
        int o = b * 256 + threadIdx.x;
        if (o < 16384) {
            int col = o >> 7, k = o & 127;
            wt1[o] = f2bf(W1[k * 128 + col]);
        } else if (o < 32768) {
            int oo = o - 16384;
            int col = oo >> 7, k = oo & 127;
            wt2[oo] = f2bf(W2[k * 128 + col]);
        } else if (o < 40960) {
            int oo = o - 32768;
            int col = oo >> 7, k = oo & 127;
            wt3[oo] = f2bf(W3[k * 64 + col]);
        }
    } else {
        int i = (b - PWB) * 256 + threadIdx.x;
        if (i < 2 * NN) degcnt_i[i] = 0;
    }
}

// ---------------- GEMM body (R11-proven): H(bf16) = X(f32->bf16) @ Wt(bf16) ----------------
template <int NOUT>
static __device__ __forceinline__ void gemm_body(const float* __restrict__ X,
                                                 const ushort* __restrict__ Wt,
                                                 ushort* __restrict__ H, int N,
                                                 int bid, int tid, char* smem) {
    char* xs = smem;              // [64 rows][128 k] bf16, swizzled
    char* wt = smem + 64 * 256;   // [NOUT cols][128 k] bf16, swizzled
    const int row0 = bid * 64;

    const uint4* Wt4 = reinterpret_cast<const uint4*>(Wt);
#pragma unroll
    for (int i = 0; i < NOUT / 16; ++i) {
        int id = tid + 256 * i;
        int col = id >> 4, c4 = id & 15;
        uint4 v = Wt4[id];
        *reinterpret_cast<uint4*>(wt + col * 256 + ((c4 * 16) ^ ((col & 7) << 4))) = v;
    }
#pragma unroll
    for (int i = 0; i < 8; ++i) {
        int id = tid + 256 * i;
        int r = id >> 5, c4 = id & 31;
        int gr = row0 + r;
        float4 v = make_float4(0.f, 0.f, 0.f, 0.f);
        if (gr < N) v = *reinterpret_cast<const float4*>(&X[(size_t)gr * 128 + c4 * 4]);
        uint2 pk;
        pk.x = pack2(v.x, v.y);
        pk.y = pack2(v.z, v.w);
        *reinterpret_cast<uint2*>(xs + r * 256 + ((c4 * 8) ^ ((r & 7) << 4))) = pk;
    }
    __syncthreads();

    const int w = tid >> 6, lane = tid & 63;
    const int rl = w * 16 + (lane & 15);
    const int kg = lane >> 4;
    f32x4 acc[NOUT / 16];
#pragma unroll
    for (int ct = 0; ct < NOUT / 16; ++ct) acc[ct] = (f32x4){0.f, 0.f, 0.f, 0.f};

#pragma unroll
    for (int ks = 0; ks < 4; ++ks) {
        const int kb = ks * 64 + kg * 16;
        short8 a = *reinterpret_cast<const short8*>(xs + rl * 256 + (kb ^ ((rl & 7) << 4)));
#pragma unroll
        for (int ct = 0; ct < NOUT / 16; ++ct) {
            int col = ct * 16 + (lane & 15);
            short8 bfr = *reinterpret_cast<const short8*>(wt + col * 256 + (kb ^ ((col & 7) << 4)));
            acc[ct] = __builtin_amdgcn_mfma_f32_16x16x32_bf16(a, bfr, acc[ct], 0, 0, 0);
        }
    }
    // C/D layout: col=lane&15, row=(lane>>4)*4+reg (m89-verified)
#pragma unroll
    for (int ct = 0; ct < NOUT / 16; ++ct) {
        int col = ct * 16 + (lane & 15);
#pragma unroll
        for (int r = 0; r < 4; ++r) {
            int gr = row0 + w * 16 + (lane >> 4) * 4 + r;
            if (gr < N) H[(size_t)gr * NOUT + col] = f2bf(acc[ct][r]);
        }
    }
}

// ---------------- merged: gemm1 + per-block hist tail (packed u64 atomic) ----------------
__global__ __launch_bounds__(256) void k_gemm1_hist(const float* __restrict__ X,
                                                    const ushort* __restrict__ Wt1,
                                                    ushort* __restrict__ H, int N,
                                                    const int* __restrict__ dst,
                                                    const float* __restrict__ ew,
                                                    uint64* __restrict__ degcnt) {
    __shared__ char smem[64 * 256 + 128 * 256];
    gemm_body<128>(X, Wt1, H, N, blockIdx.x, threadIdx.x, smem);
    // histogram tail: this block's edge slice; one u64 atomic packs (cnt, deg-fixpt)
    const int ebase = blockIdx.x * EPB;
    const int eend = (ebase + EPB < NE) ? ebase + EPB : NE;
    for (int e = ebase + threadIdx.x; e < eend; e += 256) {
        uint64 pk = (1ull << 44) | (uint64)(ew[e] * 4294967296.0f);
        atomicAdd(&degcnt[dst[e]], pk);
    }
}

// ---------------- standalone GEMMs (layers 2, 3) ----------------
template <int NOUT>
__global__ __launch_bounds__(256) void k_gemm_mfma(const float* __restrict__ X,
                                                   const ushort* __restrict__ Wt,
                                                   ushort* __restrict__ H, int N) {
    __shared__ char smem[64 * 256 + NOUT * 256];
    gemm_body<NOUT>(X, Wt, H, N, blockIdx.x, threadIdx.x, smem);
}

// ---------------- exclusive scan over cnt(hi bits of degcnt) -> rp ----------------

__global__ void k_scan1(const uint64* __restrict__ degcnt, int* __restrict__ rp,
                        int* __restrict__ bsum, int n) {
    __shared__ int tsum[256];
    const int base = blockIdx.x * 1024;
    const int t = threadIdx.x;
    int v[4], s = 0;
#pragma unroll
    for (int j = 0; j < 4; ++j) {
        int idx = base + t * 4 + j;
        v[j] = (idx < n) ? (int)(degcnt[idx] >> 44) : 0;
        s += v[j];
    }
    tsum[t] = s;
    __syncthreads();
    for (int off = 1; off < 256; off <<= 1) {
        int x = (t >= off) ? tsum[t - off] : 0;
        __syncthreads();
        tsum[t] += x;
        __syncthreads();
    }
    int excl = (t > 0) ? tsum[t - 1] : 0;
#pragma unroll
    for (int j = 0; j < 4; ++j) {
        int idx = base + t * 4 + j;
        if (idx < n) rp[idx] = excl;
        excl += v[j];
    }
    if (t == 255) bsum[blockIdx.x] = tsum[255];
}

__global__ void k_scan2(int* __restrict__ bsum, int nb) {
    __shared__ int sh[256];
    int t = threadIdx.x;
    sh[t] = (t < nb) ? bsum[t] : 0;
    __syncthreads();
    for (int off = 1; off < 256; off <<= 1) {
        int x = (t >= off) ? sh[t - off] : 0;
        __syncthreads();
        sh[t] += x;
        __syncthreads();
    }
    if (t < nb) bsum[t] = (t > 0) ? sh[t - 1] : 0;
}

// adds block offsets; cursor = rp; dinv from packed fixpt deg (fused)
__global__ void k_scan3(int* __restrict__ rp, const int* __restrict__ bsum,
                        int* __restrict__ cursor, const uint64* __restrict__ degcnt,
                        float* __restrict__ dinv, int n) {
    int i = blockIdx.x * blockDim.x + threadIdx.x;
    if (i < n) {
        int v = rp[i] + bsum[i >> 10];
        rp[i] = v;
        cursor[i] = v;
        float d = (float)(degcnt[i] & 0xFFFFFFFFFFFull) * (1.0f / 4294967296.0f);
        dinv[i] = (d > 0.f) ? rsqrtf(d) : 0.f;
    }
    if (i == 0) rp[n] = NE;
}

// ---------------- fill CSR buckets: ep[pos] = (src, norm) ----------------
__global__ void k_fill(const int* __restrict__ src, const int* __restrict__ dst,
                       const float* __restrict__ ew, const float* __restrict__ dinv,
                       int* __restrict__ cursor, uint2* __restrict__ ep, int E) {
    int e = blockIdx.x * blockDim.x + threadIdx.x;
    if (e < E) {
        int s = src[e], d = dst[e];
        int pos = atomicAdd(&cursor[d], 1);
        float nv = dinv[s] * ew[e] * dinv[d];
        ep[pos] = make_uint2((uint32)s, __float_as_uint(nv));
    }
}

// ---------------- aggregate (D=128): 4 edge-slots x 16 lanes + ep prefetch ----------------
template <int WAVES, int RELU>
__global__ void k_agg128(const int* __restrict__ rp, const uint2* __restrict__ ep,
                         const ushort* __restrict__ H, const float* __restrict__ b,
                         float* __restrict__ out, int N) {
    const int wave = threadIdx.x >> 6;
    const int lane = threadIdx.x & 63;
    const int n = blockIdx.x * WAVES + wave;
    if (n >= N) return;
    const int e0 = rp[n], e1 = rp[n + 1];
    const int slot = lane >> 4;
    const int l16 = lane & 15;

    const float4 b0 = *reinterpret_cast<const float4*>(&b[l16 * 8]);
    const float4 b1 = *reinterpret_cast<const float4*>(&b[l16 * 8 + 4]);

    float a[8] = {};
    int e = e0 + slot;
    if (e < e1) {
        uint2 p = ep[e];
        for (;;) {
            const int en = e + 4;
            uint2 pn = ep[en];   // prefetch; may read past e1 (allocated ws), never used
            float w = __uint_as_float(p.y);
            uint4 hv = *reinterpret_cast<const uint4*>(&H[(size_t)p.x * 128 + l16 * 8]);
            a[0] = fmaf(w, bf2f(hv.x & 0xffffu), a[0]);
            a[1] = fmaf(w, bf2f(hv.x >> 16), a[1]);
            a[2] = fmaf(w, bf2f(hv.y & 0xffffu), a[2]);
            a[3] = fmaf(w, bf2f(hv.y >> 16), a[3]);
            a[4] = fmaf(w, bf2f(hv.z & 0xffffu), a[4]);
            a[5] = fmaf(w, bf2f(hv.z >> 16), a[5]);
            a[6] = fmaf(w, bf2f(hv.w & 0xffffu), a[6]);
            a[7] = fmaf(w, bf2f(hv.w >> 16), a[7]);
            e = en;
            if (e >= e1) break;
            p = pn;
        }
    }
#pragma unroll
    for (int j = 0; j < 8; ++j) {
        a[j] += __shfl_xor(a[j], 32);
        a[j] += __shfl_xor(a[j], 16);
    }
    if (lane < 16) {
        float4 o0 = make_float4(a[0] + b0.x, a[1] + b0.y, a[2] + b0.z, a[3] + b0.w);
        float4 o1 = make_float4(a[4] + b1.x, a[5] + b1.y, a[6] + b1.z, a[7] + b1.w);
        if (RELU) {
            o0.x = fmaxf(o0.x, 0.f); o0.y = fmaxf(o0.y, 0.f);
            o0.z = fmaxf(o0.z, 0.f); o0.w = fmaxf(o0.w, 0.f);
            o1.x = fmaxf(o1.x, 0.f); o1.y = fmaxf(o1.y, 0.f);
            o1.z = fmaxf(o1.z, 0.f); o1.w = fmaxf(o1.w, 0.f);
        }
        float* op = &out[(size_t)n * 128 + l16 * 8];
        *reinterpret_cast<float4*>(op) = o0;
        *reinterpret_cast<float4*>(op + 4) = o1;
    }
}

// ---------------- aggregate (D=64): 8 edge-slots x 8 lanes + ep prefetch ----------------
template <int WAVES, int RELU>
__global__ void k_agg64(const int* __restrict__ rp, const uint2* __restrict__ ep,
                        const ushort* __restrict__ H, const float* __restrict__ b,
                        float* __restrict__ out, int N) {
    const int wave = threadIdx.x >> 6;
    const int lane = threadIdx.x & 63;
    const int n = blockIdx.x * WAVES + wave;
    if (n >= N) return;
    const int e0 = rp[n], e1 = rp[n + 1];
    const int slot = lane >> 3;
    const int l8 = lane & 7;

    const float4 b0 = *reinterpret_cast<const float4*>(&b[l8 * 8]);
    const float4 b1 = *reinterpret_cast<const float4*>(&b[l8 * 8 + 4]);

    float a[8] = {};
    int e = e0 + slot;
    if (e < e1) {
        uint2 p = ep[e];
        for (;;) {
            const int en = e + 8;
            uint2 pn = ep[en];
            float w = __uint_as_float(p.y);
            uint4 hv = *reinterpret_cast<const uint4*>(&H[(size_t)p.x * 64 + l8 * 8]);
            a[0] = fmaf(w, bf2f(hv.x & 0xffffu), a[0]);
            a[1] = fmaf(w, bf2f(hv.x >> 16), a[1]);
            a[2] = fmaf(w, bf2f(hv.y & 0xffffu), a[2]);
            a[3] = fmaf(w, bf2f(hv.y >> 16), a[3]);
            a[4] = fmaf(w, bf2f(hv.z & 0xffffu), a[4]);
            a[5] = fmaf(w, bf2f(hv.z >> 16), a[5]);
            a[6] = fmaf(w, bf2f(hv.w & 0xffffu), a[6]);
            a[7] = fmaf(w, bf2f(hv.w >> 16), a[7]);
            e = en;
            if (e >= e1) break;
            p = pn;
        }
    }
#pragma unroll
    for (int j = 0; j < 8; ++j) {
        a[j] += __shfl_xor(a[j], 8);
        a[j] += __shfl_xor(a[j], 16);
        a[j] += __shfl_xor(a[j], 32);
    }
    if (lane < 8) {
        float4 o0 = make_float4(a[0] + b0.x, a[1] + b0.y, a[2] + b0.z, a[3] + b0.w);
        float4 o1 = make_float4(a[4] + b1.x, a[5] + b1.y, a[6] + b1.z, a[7] + b1.w);
        if (RELU) {
            o0.x = fmaxf(o0.x, 0.f); o0.y = fmaxf(o0.y, 0.f);
            o0.z = fmaxf(o0.z, 0.f); o0.w = fmaxf(o0.w, 0.f);
            o1.x = fmaxf(o1.x, 0.f); o1.y = fmaxf(o1.y, 0.f);
            o1.z = fmaxf(o1.z, 0.f); o1.w = fmaxf(o1.w, 0.f);
        }
        float* op = &out[(size_t)n * 64 + l8 * 8];
        *reinterpret_cast<float4*>(op) = o0;
        *reinterpret_cast<float4*>(op + 4) = o1;
    }
}

// ---------------- launch ----------------

extern "C" void kernel_launch(void* const* d_in, const int* in_sizes, int n_in,
                              void* d_out, int out_size, void* d_ws, size_t ws_size,
                              hipStream_t stream) {
    const float* x  = (const float*)d_in[0];
    const int*   ei = (const int*)d_in[1];
    const float* ew = (const float*)d_in[2];
    const float* W1 = (const float*)d_in[3];
    const float* b1 = (const float*)d_in[4];
    const float* W2 = (const float*)d_in[5];
    const float* b2 = (const float*)d_in[6];
    const float* W3 = (const float*)d_in[7];
    const float* b3 = (const float*)d_in[8];

    const int* src = ei;
    const int* dst = ei + NE;

    // ws layout (same footprint as R13: 57.6 MB)
    float*  ws     = (float*)d_ws;
    uint64* degcnt = (uint64*)ws;                 // NN u64 (packed cnt|deg) = 2NN ints
    int*    rp     = (int*)(ws + 2 * NN);         // NN+1 i
    int*    bsum   = (int*)(ws + 3 * NN + 64);    // 128 i
    uint2*  ep     = (uint2*)(ws + 3 * NN + 256); // NE uint2 (src, norm)
    ushort* h1     = (ushort*)(ws + 3 * NN + 256 + 2 * NE); // NN*128 bf16
    ushort* h2     = h1 + (size_t)NN * 128;                 // NN*128 bf16
    ushort* h3     = h1;                                    // NN*64 bf16 (aliases h1)
    ushort* wt1    = h2 + (size_t)NN * 128;       // 128*128 bf16 (W1^T)
    ushort* wt2    = wt1 + 128 * 128;             // 128*128 bf16
    ushort* wt3    = wt2 + 128 * 128;             // 64*128 bf16
    int*    cursor = (int*)h2;                    // NN i (aliases h2; dead before gemm2)

    float* out0 = (float*)d_out;                  // [NN,128]
    float* out1 = out0 + NN * 128;                // [NN,128]
    float* out2 = out1 + NN * 128;                // [NN,64]
    float* dinv = out2;                           // NN f scratch in out2 (dead until agg64)

    const int B = 256;
    const int NB_SCAN = (NN + 1023) / 1024;       // 98

    // prepW + zero packed degcnt (one kernel)
    k_prep_zero<<<PWB + ZB, B, 0, stream>>>(W1, W2, W3, wt1, wt2, wt3, (int*)degcnt);

    // merged: layer-1 GEMM; each block appends its 410-edge packed-histogram tail
    k_gemm1_hist<<<GB1, 256, 0, stream>>>(x, wt1, h1, NN, dst, ew, degcnt);

    k_scan1<<<NB_SCAN, 256, 0, stream>>>(degcnt, rp, bsum, NN);
    k_scan2<<<1, 256, 0, stream>>>(bsum, NB_SCAN);
    k_scan3<<<(NN + B - 1) / B, B, 0, stream>>>(rp, bsum, cursor, degcnt, dinv, NN);
    k_fill<<<(NE + B - 1) / B, B, 0, stream>>>(src, dst, ew, dinv, cursor, ep, NE);

    // ----- layer 1 aggregate -----
    k_agg128<4, 1><<<(NN + 3) / 4, 256, 0, stream>>>(rp, ep, h1, b1, out0, NN);

    // ----- layer 2 -----
    k_gemm_mfma<128><<<GB1, 256, 0, stream>>>(out0, wt2, h2, NN);
    k_agg128<4, 1><<<(NN + 3) / 4, 256, 0, stream>>>(rp, ep, h2, b2, out1, NN);

    // ----- layer 3 -----
    k_gemm_mfma<64><<<GB1, 256, 0, stream>>>(out1, wt3, h3, NN);
    k_agg64<4, 0><<<(NN + 3) / 4, 256, 0, stream>>>(rp, ep, h3, b3, out2, NN);
}

// Round 15
// 234.973 us; speedup vs baseline: 1.2337x; 1.0184x over previous
//
#include <hip/hip_runtime.h>

#define NN 100000
#define NE 640000
#define GB1 ((NN + 63) / 64)        // 1563 gemm blocks (64 rows each)
#define EPB ((NE + GB1 - 1) / GB1)  // 410 edges per gemm block (hist tail)
#define PWB 160                     // prepW blocks (40960 elems / 256)
#define ZB  ((2 * NN + 64 + 255) / 256) // zero blocks (degcnt + base_ctr pad)

typedef unsigned int uint32;
typedef unsigned long long uint64;
typedef __attribute__((ext_vector_type(8))) short short8;
typedef __attribute__((ext_vector_type(4))) float f32x4;

static __device__ __forceinline__ ushort f2bf(float f) {
    uint32 u = __float_as_uint(f);
    u = (u + 0x7fffu + ((u >> 16) & 1u)) >> 16;
    return (ushort)u;
}
static __device__ __forceinline__ float bf2f(uint32 bits16) {
    return __uint_as_float(bits16 << 16);
}
static __device__ __forceinline__ uint32 pack2(float a, float b) {
    return (uint32)f2bf(a) | ((uint32)f2bf(b) << 16);
}

// ---------------- prepW (blocks 0..159) + zero degcnt/base_ctr (blocks 160+) ----------------
__global__ void k_prep_zero(const float* __restrict__ W1, const float* __restrict__ W2,
                            const float* __restrict__ W3, ushort* __restrict__ wt1,
                            ushort* __restrict__ wt2, ushort* __restrict__ wt3,
                            int* __restrict__ zbase) {
    const int b = blockIdx.x;
    if (b < PWB) {
        int o = b * 256 + threadIdx.x;
        if (o < 16384) {
            int col = o >> 7, k = o & 127;
            wt1[o] = f2bf(W1[k * 128 + col]);
        } else if (o < 32768) {
            int oo = o - 16384;
            int col = oo >> 7, k = oo & 127;
            wt2[oo] = f2bf(W2[k * 128 + col]);
        } else if (o < 40960) {
            int oo = o - 32768;
            int col = oo >> 7, k = oo & 127;
            wt3[oo] = f2bf(W3[k * 64 + col]);
        }
    } else {
        int i = (b - PWB) * 256 + threadIdx.x;
        if (i < 2 * NN + 64) zbase[i] = 0;   // degcnt (2NN ints) + base_ctr pad
    }
}

// ---------------- GEMM body (R11-proven): H(bf16) = X(f32->bf16) @ Wt(bf16) ----------------
template <int NOUT>
static __device__ __forceinline__ void gemm_body(const float* __restrict__ X,
                                                 const ushort* __restrict__ Wt,
                                                 ushort* __restrict__ H, int N,
                                                 int bid, int tid, char* smem) {
    char* xs = smem;              // [64 rows][128 k] bf16, swizzled
    char* wt = smem + 64 * 256;   // [NOUT cols][128 k] bf16, swizzled
    const int row0 = bid * 64;

    const uint4* Wt4 = reinterpret_cast<const uint4*>(Wt);
#pragma unroll
    for (int i = 0; i < NOUT / 16; ++i) {
        int id = tid + 256 * i;
        int col = id >> 4, c4 = id & 15;
        uint4 v = Wt4[id];
        *reinterpret_cast<uint4*>(wt + col * 256 + ((c4 * 16) ^ ((col & 7) << 4))) = v;
    }
#pragma unroll
    for (int i = 0; i < 8; ++i) {
        int id = tid + 256 * i;
        int r = id >> 5, c4 = id & 31;
        int gr = row0 + r;
        float4 v = make_float4(0.f, 0.f, 0.f, 0.f);
        if (gr < N) v = *reinterpret_cast<const float4*>(&X[(size_t)gr * 128 + c4 * 4]);
        uint2 pk;
        pk.x = pack2(v.x, v.y);
        pk.y = pack2(v.z, v.w);
        *reinterpret_cast<uint2*>(xs + r * 256 + ((c4 * 8) ^ ((r & 7) << 4))) = pk;
    }
    __syncthreads();

    const int w = tid >> 6, lane = tid & 63;
    const int rl = w * 16 + (lane & 15);
    const int kg = lane >> 4;
    f32x4 acc[NOUT / 16];
#pragma unroll
    for (int ct = 0; ct < NOUT / 16; ++ct) acc[ct] = (f32x4){0.f, 0.f, 0.f, 0.f};

#pragma unroll
    for (int ks = 0; ks < 4; ++ks) {
        const int kb = ks * 64 + kg * 16;
        short8 a = *reinterpret_cast<const short8*>(xs + rl * 256 + (kb ^ ((rl & 7) << 4)));
#pragma unroll
        for (int ct = 0; ct < NOUT / 16; ++ct) {
            int col = ct * 16 + (lane & 15);
            short8 bfr = *reinterpret_cast<const short8*>(wt + col * 256 + (kb ^ ((col & 7) << 4)));
            acc[ct] = __builtin_amdgcn_mfma_f32_16x16x32_bf16(a, bfr, acc[ct], 0, 0, 0);
        }
    }
    // C/D layout: col=lane&15, row=(lane>>4)*4+reg (m89-verified)
#pragma unroll
    for (int ct = 0; ct < NOUT / 16; ++ct) {
        int col = ct * 16 + (lane & 15);
#pragma unroll
        for (int r = 0; r < 4; ++r) {
            int gr = row0 + w * 16 + (lane >> 4) * 4 + r;
            if (gr < N) H[(size_t)gr * NOUT + col] = f2bf(acc[ct][r]);
        }
    }
}

// ---------------- merged: gemm1 + per-block hist tail (packed u64 atomic) ----------------
__global__ __launch_bounds__(256) void k_gemm1_hist(const float* __restrict__ X,
                                                    const ushort* __restrict__ Wt1,
                                                    ushort* __restrict__ H, int N,
                                                    const int* __restrict__ dst,
                                                    const float* __restrict__ ew,
                                                    uint64* __restrict__ degcnt) {
    __shared__ char smem[64 * 256 + 128 * 256];
    gemm_body<128>(X, Wt1, H, N, blockIdx.x, threadIdx.x, smem);
    const int ebase = blockIdx.x * EPB;
    const int eend = (ebase + EPB < NE) ? ebase + EPB : NE;
    for (int e = ebase + threadIdx.x; e < eend; e += 256) {
        uint64 pk = (1ull << 44) | (uint64)(ew[e] * 4294967296.0f);
        atomicAdd(&degcnt[dst[e]], pk);
    }
}

// ---------------- standalone GEMMs (layers 2, 3) ----------------
template <int NOUT>
__global__ __launch_bounds__(256) void k_gemm_mfma(const float* __restrict__ X,
                                                   const ushort* __restrict__ Wt,
                                                   ushort* __restrict__ H, int N) {
    __shared__ char smem[64 * 256 + NOUT * 256];
    gemm_body<NOUT>(X, Wt, H, N, blockIdx.x, threadIdx.x, smem);
}

// ---------------- single-kernel scan: rp/rpe/cursor/dinv via atomic block base ----------------
// Bucket bases assigned in block-arrival order (valid: aggs read explicit [rp,rpe)).
__global__ void k_scan(const uint64* __restrict__ degcnt, int* __restrict__ rp,
                       int* __restrict__ rpe, int* __restrict__ cursor,
                       float* __restrict__ dinv, int* __restrict__ base_ctr, int n) {
    __shared__ int tsum[256];
    __shared__ int sbase;
    const int base = blockIdx.x * 1024;
    const int t = threadIdx.x;
    int v[4], s = 0;
    uint64 dc[4];
#pragma unroll
    for (int j = 0; j < 4; ++j) {
        int idx = base + t * 4 + j;
        dc[j] = (idx < n) ? degcnt[idx] : 0ull;
        v[j] = (int)(dc[j] >> 44);
        s += v[j];
    }
    tsum[t] = s;
    __syncthreads();
    for (int off = 1; off < 256; off <<= 1) {
        int x = (t >= off) ? tsum[t - off] : 0;
        __syncthreads();
        tsum[t] += x;
        __syncthreads();
    }
    if (t == 255) sbase = atomicAdd(base_ctr, tsum[255]);
    __syncthreads();
    int excl = sbase + ((t > 0) ? tsum[t - 1] : 0);
#pragma unroll
    for (int j = 0; j < 4; ++j) {
        int idx = base + t * 4 + j;
        if (idx < n) {
            rp[idx] = excl;
            rpe[idx] = excl + v[j];
            cursor[idx] = excl;
            float d = (float)(dc[j] & 0xFFFFFFFFFFFull) * (1.0f / 4294967296.0f);
            dinv[idx] = (d > 0.f) ? rsqrtf(d) : 0.f;
        }
        excl += v[j];
    }
}

// ---------------- fill CSR buckets: ep[pos] = (src, norm) ----------------
__global__ void k_fill(const int* __restrict__ src, const int* __restrict__ dst,
                       const float* __restrict__ ew, const float* __restrict__ dinv,
                       int* __restrict__ cursor, uint2* __restrict__ ep, int E) {
    int e = blockIdx.x * blockDim.x + threadIdx.x;
    if (e < E) {
        int s = src[e], d = dst[e];
        int pos = atomicAdd(&cursor[d], 1);
        float nv = dinv[s] * ew[e] * dinv[d];
        ep[pos] = make_uint2((uint32)s, __float_as_uint(nv));
    }
}

// ---------------- aggregate (D=128): 4 edge-slots x 16 lanes + ep prefetch ----------------
template <int WAVES, int RELU>
__global__ void k_agg128(const int* __restrict__ rp, const int* __restrict__ rpe,
                         const uint2* __restrict__ ep, const ushort* __restrict__ H,
                         const float* __restrict__ b, float* __restrict__ out, int N) {
    const int wave = threadIdx.x >> 6;
    const int lane = threadIdx.x & 63;
    const int n = blockIdx.x * WAVES + wave;
    if (n >= N) return;
    const int e0 = rp[n], e1 = rpe[n];
    const int slot = lane >> 4;
    const int l16 = lane & 15;

    const float4 b0 = *reinterpret_cast<const float4*>(&b[l16 * 8]);
    const float4 b1 = *reinterpret_cast<const float4*>(&b[l16 * 8 + 4]);

    float a[8] = {};
    int e = e0 + slot;
    if (e < e1) {
        uint2 p = ep[e];
        for (;;) {
            const int en = e + 4;
            uint2 pn = ep[en];   // prefetch; may read past e1 (allocated ws), never used
            float w = __uint_as_float(p.y);
            uint4 hv = *reinterpret_cast<const uint4*>(&H[(size_t)p.x * 128 + l16 * 8]);
            a[0] = fmaf(w, bf2f(hv.x & 0xffffu), a[0]);
            a[1] = fmaf(w, bf2f(hv.x >> 16), a[1]);
            a[2] = fmaf(w, bf2f(hv.y & 0xffffu), a[2]);
            a[3] = fmaf(w, bf2f(hv.y >> 16), a[3]);
            a[4] = fmaf(w, bf2f(hv.z & 0xffffu), a[4]);
            a[5] = fmaf(w, bf2f(hv.z >> 16), a[5]);
            a[6] = fmaf(w, bf2f(hv.w & 0xffffu), a[6]);
            a[7] = fmaf(w, bf2f(hv.w >> 16), a[7]);
            e = en;
            if (e >= e1) break;
            p = pn;
        }
    }
#pragma unroll
    for (int j = 0; j < 8; ++j) {
        a[j] += __shfl_xor(a[j], 32);
        a[j] += __shfl_xor(a[j], 16);
    }
    if (lane < 16) {
        float4 o0 = make_float4(a[0] + b0.x, a[1] + b0.y, a[2] + b0.z, a[3] + b0.w);
        float4 o1 = make_float4(a[4] + b1.x, a[5] + b1.y, a[6] + b1.z, a[7] + b1.w);
        if (RELU) {
            o0.x = fmaxf(o0.x, 0.f); o0.y = fmaxf(o0.y, 0.f);
            o0.z = fmaxf(o0.z, 0.f); o0.w = fmaxf(o0.w, 0.f);
            o1.x = fmaxf(o1.x, 0.f); o1.y = fmaxf(o1.y, 0.f);
            o1.z = fmaxf(o1.z, 0.f); o1.w = fmaxf(o1.w, 0.f);
        }
        float* op = &out[(size_t)n * 128 + l16 * 8];
        *reinterpret_cast<float4*>(op) = o0;
        *reinterpret_cast<float4*>(op + 4) = o1;
    }
}

// ---------------- aggregate (D=64): 8 edge-slots x 8 lanes + ep prefetch ----------------
template <int WAVES, int RELU>
__global__ void k_agg64(const int* __restrict__ rp, const int* __restrict__ rpe,
                        const uint2* __restrict__ ep, const ushort* __restrict__ H,
                        const float* __restrict__ b, float* __restrict__ out, int N) {
    const int wave = threadIdx.x >> 6;
    const int lane = threadIdx.x & 63;
    const int n = blockIdx.x * WAVES + wave;
    if (n >= N) return;
    const int e0 = rp[n], e1 = rpe[n];
    const int slot = lane >> 3;
    const int l8 = lane & 7;

    const float4 b0 = *reinterpret_cast<const float4*>(&b[l8 * 8]);
    const float4 b1 = *reinterpret_cast<const float4*>(&b[l8 * 8 + 4]);

    float a[8] = {};
    int e = e0 + slot;
    if (e < e1) {
        uint2 p = ep[e];
        for (;;) {
            const int en = e + 8;
            uint2 pn = ep[en];
            float w = __uint_as_float(p.y);
            uint4 hv = *reinterpret_cast<const uint4*>(&H[(size_t)p.x * 64 + l8 * 8]);
            a[0] = fmaf(w, bf2f(hv.x & 0xffffu), a[0]);
            a[1] = fmaf(w, bf2f(hv.x >> 16), a[1]);
            a[2] = fmaf(w, bf2f(hv.y & 0xffffu), a[2]);
            a[3] = fmaf(w, bf2f(hv.y >> 16), a[3]);
            a[4] = fmaf(w, bf2f(hv.z & 0xffffu), a[4]);
            a[5] = fmaf(w, bf2f(hv.z >> 16), a[5]);
            a[6] = fmaf(w, bf2f(hv.w & 0xffffu), a[6]);
            a[7] = fmaf(w, bf2f(hv.w >> 16), a[7]);
            e = en;
            if (e >= e1) break;
            p = pn;
        }
    }
#pragma unroll
    for (int j = 0; j < 8; ++j) {
        a[j] += __shfl_xor(a[j], 8);
        a[j] += __shfl_xor(a[j], 16);
        a[j] += __shfl_xor(a[j], 32);
    }
    if (lane < 8) {
        float4 o0 = make_float4(a[0] + b0.x, a[1] + b0.y, a[2] + b0.z, a[3] + b0.w);
        float4 o1 = make_float4(a[4] + b1.x, a[5] + b1.y, a[6] + b1.z, a[7] + b1.w);
        if (RELU) {
            o0.x = fmaxf(o0.x, 0.f); o0.y = fmaxf(o0.y, 0.f);
            o0.z = fmaxf(o0.z, 0.f); o0.w = fmaxf(o0.w, 0.f);
            o1.x = fmaxf(o1.x, 0.f); o1.y = fmaxf(o1.y, 0.f);
            o1.z = fmaxf(o1.z, 0.f); o1.w = fmaxf(o1.w, 0.f);
        }
        float* op = &out[(size_t)n * 64 + l8 * 8];
        *reinterpret_cast<float4*>(op) = o0;
        *reinterpret_cast<float4*>(op + 4) = o1;
    }
}

// ---------------- launch ----------------

extern "C" void kernel_launch(void* const* d_in, const int* in_sizes, int n_in,
                              void* d_out, int out_size, void* d_ws, size_t ws_size,
                              hipStream_t stream) {
    const float* x  = (const float*)d_in[0];
    const int*   ei = (const int*)d_in[1];
    const float* ew = (const float*)d_in[2];
    const float* W1 = (const float*)d_in[3];
    const float* b1 = (const float*)d_in[4];
    const float* W2 = (const float*)d_in[5];
    const float* b2 = (const float*)d_in[6];
    const float* W3 = (const float*)d_in[7];
    const float* b3 = (const float*)d_in[8];

    const int* src = ei;
    const int* dst = ei + NE;

    // ws layout (~58 MB)
    float*  ws       = (float*)d_ws;
    uint64* degcnt   = (uint64*)ws;                  // NN u64 = 2NN ints
    int*    base_ctr = (int*)(ws + 2 * NN);          // 1 int (zeroed with degcnt)
    int*    rp       = (int*)(ws + 2 * NN + 64);     // NN i
    int*    rpe      = (int*)(ws + 3 * NN + 64);     // NN i
    uint2*  ep       = (uint2*)(ws + 4 * NN + 128);  // NE uint2
    ushort* h1       = (ushort*)(ws + 4 * NN + 128 + 2 * NE); // NN*128 bf16
    ushort* h2       = h1 + (size_t)NN * 128;                 // NN*128 bf16
    ushort* h3       = h1;                                    // NN*64 bf16 (aliases h1)
    ushort* wt1      = h2 + (size_t)NN * 128;        // 128*128 bf16
    ushort* wt2      = wt1 + 128 * 128;              // 128*128 bf16
    ushort* wt3      = wt2 + 128 * 128;              // 64*128 bf16
    int*    cursor   = (int*)h2;                     // NN i (aliases h2; dead before gemm2)

    float* out0 = (float*)d_out;                     // [NN,128]
    float* out1 = out0 + NN * 128;                   // [NN,128]
    float* out2 = out1 + NN * 128;                   // [NN,64]
    float* dinv = out2;                              // NN f scratch (dead until agg64)

    const int B = 256;
    const int NB_SCAN = (NN + 1023) / 1024;          // 98

    // prepW + zero degcnt/base_ctr (one kernel)
    k_prep_zero<<<PWB + ZB, B, 0, stream>>>(W1, W2, W3, wt1, wt2, wt3, (int*)degcnt);

    // merged: layer-1 GEMM; each block appends its 410-edge packed-histogram tail
    k_gemm1_hist<<<GB1, 256, 0, stream>>>(x, wt1, h1, NN, dst, ew, degcnt);

    // single-kernel scan (rp/rpe/cursor/dinv)
    k_scan<<<NB_SCAN, 256, 0, stream>>>(degcnt, rp, rpe, cursor, dinv, base_ctr, NN);
    k_fill<<<(NE + B - 1) / B, B, 0, stream>>>(src, dst, ew, dinv, cursor, ep, NE);

    // ----- layer 1 aggregate -----
    k_agg128<4, 1><<<(NN + 3) / 4, 256, 0, stream>>>(rp, rpe, ep, h1, b1, out0, NN);

    // ----- layer 2 -----
    k_gemm_mfma<128><<<GB1, 256, 0, stream>>>(out0, wt2, h2, NN);
    k_agg128<4, 1><<<(NN + 3) / 4, 256, 0, stream>>>(rp, rpe, ep, h2, b2, out1, NN);

    // ----- layer 3 -----
    k_gemm_mfma<64><<<GB1, 256, 0, stream>>>(out1, wt3, h3, NN);
    k_agg64<4, 0><<<(NN + 3) / 4, 256, 0, stream>>>(rp, rpe, ep, h3, b3, out2, NN);
}

// Round 16
// 227.379 us; speedup vs baseline: 1.2749x; 1.0334x over previous
//
#include <hip/hip_runtime.h>

#define NN 100000
#define NE 640000
#define GB1 ((NN + 63) / 64)        // 1563 gemm blocks (64 rows each)
#define EPB ((NE + GB1 - 1) / GB1)  // 410 edges per gemm block (hist tail)
#define PWB 160                     // prepW blocks (40960 elems / 256)
#define ZB  ((2 * NN + 64 + 255) / 256) // zero blocks (degcnt + base_ctr pad)

typedef unsigned int uint32;
typedef unsigned long long uint64;
typedef __attribute__((ext_vector_type(8))) short short8;
typedef __attribute__((ext_vector_type(4))) float f32x4;

static __device__ __forceinline__ ushort f2bf(float f) {
    uint32 u = __float_as_uint(f);
    u = (u + 0x7fffu + ((u >> 16) & 1u)) >> 16;
    return (ushort)u;
}
static __device__ __forceinline__ float bf2f(uint32 bits16) {
    return __uint_as_float(bits16 << 16);
}
static __device__ __forceinline__ uint32 pack2(float a, float b) {
    return (uint32)f2bf(a) | ((uint32)f2bf(b) << 16);
}

// ---------------- prepW (blocks 0..159) + zero degcnt/base_ctr (blocks 160+) ----------------
__global__ void k_prep_zero(const float* __restrict__ W1, const float* __restrict__ W2,
                            const float* __restrict__ W3, ushort* __restrict__ wt1,
                            ushort* __restrict__ wt2, ushort* __restrict__ wt3,
                            int* __restrict__ zbase) {
    const int b = blockIdx.x;
    if (b < PWB) {
        int o = b * 256 + threadIdx.x;
        if (o < 16384) {
            int col = o >> 7, k = o & 127;
            wt1[o] = f2bf(W1[k * 128 + col]);
        } else if (o < 32768) {
            int oo = o - 16384;
            int col = oo >> 7, k = oo & 127;
            wt2[oo] = f2bf(W2[k * 128 + col]);
        } else if (o < 40960) {
            int oo = o - 32768;
            int col = oo >> 7, k = oo & 127;
            wt3[oo] = f2bf(W3[k * 64 + col]);
        }
    } else {
        int i = (b - PWB) * 256 + threadIdx.x;
        if (i < 2 * NN + 64) zbase[i] = 0;   // degcnt (2NN ints) + base_ctr pad
    }
}

// ---------------- GEMM body (R11-proven): H(bf16) = X(f32->bf16) @ Wt(bf16) ----------------
template <int NOUT>
static __device__ __forceinline__ void gemm_body(const float* __restrict__ X,
                                                 const ushort* __restrict__ Wt,
                                                 ushort* __restrict__ H, int N,
                                                 int bid, int tid, char* smem) {
    char* xs = smem;              // [64 rows][128 k] bf16, swizzled
    char* wt = smem + 64 * 256;   // [NOUT cols][128 k] bf16, swizzled
    const int row0 = bid * 64;

    const uint4* Wt4 = reinterpret_cast<const uint4*>(Wt);
#pragma unroll
    for (int i = 0; i < NOUT / 16; ++i) {
        int id = tid + 256 * i;
        int col = id >> 4, c4 = id & 15;
        uint4 v = Wt4[id];
        *reinterpret_cast<uint4*>(wt + col * 256 + ((c4 * 16) ^ ((col & 7) << 4))) = v;
    }
#pragma unroll
    for (int i = 0; i < 8; ++i) {
        int id = tid + 256 * i;
        int r = id >> 5, c4 = id & 31;
        int gr = row0 + r;
        float4 v = make_float4(0.f, 0.f, 0.f, 0.f);
        if (gr < N) v = *reinterpret_cast<const float4*>(&X[(size_t)gr * 128 + c4 * 4]);
        uint2 pk;
        pk.x = pack2(v.x, v.y);
        pk.y = pack2(v.z, v.w);
        *reinterpret_cast<uint2*>(xs + r * 256 + ((c4 * 8) ^ ((r & 7) << 4))) = pk;
    }
    __syncthreads();

    const int w = tid >> 6, lane = tid & 63;
    const int rl = w * 16 + (lane & 15);
    const int kg = lane >> 4;
    f32x4 acc[NOUT / 16];
#pragma unroll
    for (int ct = 0; ct < NOUT / 16; ++ct) acc[ct] = (f32x4){0.f, 0.f, 0.f, 0.f};

#pragma unroll
    for (int ks = 0; ks < 4; ++ks) {
        const int kb = ks * 64 + kg * 16;
        short8 a = *reinterpret_cast<const short8*>(xs + rl * 256 + (kb ^ ((rl & 7) << 4)));
#pragma unroll
        for (int ct = 0; ct < NOUT / 16; ++ct) {
            int col = ct * 16 + (lane & 15);
            short8 bfr = *reinterpret_cast<const short8*>(wt + col * 256 + (kb ^ ((col & 7) << 4)));
            acc[ct] = __builtin_amdgcn_mfma_f32_16x16x32_bf16(a, bfr, acc[ct], 0, 0, 0);
        }
    }
    // C/D layout: col=lane&15, row=(lane>>4)*4+reg (m89-verified)
#pragma unroll
    for (int ct = 0; ct < NOUT / 16; ++ct) {
        int col = ct * 16 + (lane & 15);
#pragma unroll
        for (int r = 0; r < 4; ++r) {
            int gr = row0 + w * 16 + (lane >> 4) * 4 + r;
            if (gr < N) H[(size_t)gr * NOUT + col] = f2bf(acc[ct][r]);
        }
    }
}

// ---------------- merged: gemm1 + per-block hist tail (packed u64 atomic) ----------------
__global__ __launch_bounds__(256) void k_gemm1_hist(const float* __restrict__ X,
                                                    const ushort* __restrict__ Wt1,
                                                    ushort* __restrict__ H, int N,
                                                    const int* __restrict__ dst,
                                                    const float* __restrict__ ew,
                                                    uint64* __restrict__ degcnt) {
    __shared__ char smem[64 * 256 + 128 * 256];
    gemm_body<128>(X, Wt1, H, N, blockIdx.x, threadIdx.x, smem);
    const int ebase = blockIdx.x * EPB;
    const int eend = (ebase + EPB < NE) ? ebase + EPB : NE;
    for (int e = ebase + threadIdx.x; e < eend; e += 256) {
        uint64 pk = (1ull << 44) | (uint64)(ew[e] * 4294967296.0f);
        atomicAdd(&degcnt[dst[e]], pk);
    }
}

// ---------------- standalone GEMMs (layers 2, 3) ----------------
template <int NOUT>
__global__ __launch_bounds__(256) void k_gemm_mfma(const float* __restrict__ X,
                                                   const ushort* __restrict__ Wt,
                                                   ushort* __restrict__ H, int N) {
    __shared__ char smem[64 * 256 + NOUT * 256];
    gemm_body<NOUT>(X, Wt, H, N, blockIdx.x, threadIdx.x, smem);
}

// ---------------- single-kernel scan: rp/rpe/cursor/dinv via atomic block base ----------------
__global__ void k_scan(const uint64* __restrict__ degcnt, int* __restrict__ rp,
                       int* __restrict__ rpe, int* __restrict__ cursor,
                       float* __restrict__ dinv, int* __restrict__ base_ctr, int n) {
    __shared__ int tsum[256];
    __shared__ int sbase;
    const int base = blockIdx.x * 1024;
    const int t = threadIdx.x;
    int v[4], s = 0;
    uint64 dc[4];
#pragma unroll
    for (int j = 0; j < 4; ++j) {
        int idx = base + t * 4 + j;
        dc[j] = (idx < n) ? degcnt[idx] : 0ull;
        v[j] = (int)(dc[j] >> 44);
        s += v[j];
    }
    tsum[t] = s;
    __syncthreads();
    for (int off = 1; off < 256; off <<= 1) {
        int x = (t >= off) ? tsum[t - off] : 0;
        __syncthreads();
        tsum[t] += x;
        __syncthreads();
    }
    if (t == 255) sbase = atomicAdd(base_ctr, tsum[255]);
    __syncthreads();
    int excl = sbase + ((t > 0) ? tsum[t - 1] : 0);
#pragma unroll
    for (int j = 0; j < 4; ++j) {
        int idx = base + t * 4 + j;
        if (idx < n) {
            rp[idx] = excl;
            rpe[idx] = excl + v[j];
            cursor[idx] = excl;
            float d = (float)(dc[j] & 0xFFFFFFFFFFFull) * (1.0f / 4294967296.0f);
            dinv[idx] = (d > 0.f) ? rsqrtf(d) : 0.f;
        }
        excl += v[j];
    }
}

// ---------------- fill CSR buckets: ep[pos] = (src, norm) ----------------
__global__ void k_fill(const int* __restrict__ src, const int* __restrict__ dst,
                       const float* __restrict__ ew, const float* __restrict__ dinv,
                       int* __restrict__ cursor, uint2* __restrict__ ep, int E) {
    int e = blockIdx.x * blockDim.x + threadIdx.x;
    if (e < E) {
        int s = src[e], d = dst[e];
        int pos = atomicAdd(&cursor[d], 1);
        float nv = dinv[s] * ew[e] * dinv[d];
        ep[pos] = make_uint2((uint32)s, __float_as_uint(nv));
    }
}

// ---------------- aggregate (D=128): 2 nodes/wave x 4 edge-slots x 16 lanes ----------------
template <int RELU>
__global__ void k_agg128(const int* __restrict__ rp, const int* __restrict__ rpe,
                         const uint2* __restrict__ ep, const ushort* __restrict__ H,
                         const float* __restrict__ b, float* __restrict__ out, int N) {
    const int wave = threadIdx.x >> 6;
    const int lane = threadIdx.x & 63;
    const int nA = blockIdx.x * 8 + wave * 2;
    const int nB = nA + 1;
    if (nA >= N) return;
    const int slot = lane >> 4;
    const int l16 = lane & 15;
    const uint4* H4 = reinterpret_cast<const uint4*>(H);

    const float4 b0 = *reinterpret_cast<const float4*>(&b[l16 * 8]);
    const float4 b1 = *reinterpret_cast<const float4*>(&b[l16 * 8 + 4]);

    int eA = rp[nA] + slot, e1A = rpe[nA];
    int eB = 0, e1B = 0;
    if (nB < N) { eB = rp[nB] + slot; e1B = rpe[nB]; }

    float aA[8] = {}, aB[8] = {};
    bool vA = eA < e1A, vB = eB < e1B;
    uint2 pA, pB;
    if (vA) pA = ep[eA];
    if (vB) pB = ep[eB];
    while (vA || vB) {
        uint4 hA, hB;
        if (vA) hA = H4[(size_t)pA.x * 16 + l16];
        if (vB) hB = H4[(size_t)pB.x * 16 + l16];
        const bool vnA = (eA + 4) < e1A, vnB = (eB + 4) < e1B;
        uint2 pnA, pnB;
        if (vnA) pnA = ep[eA + 4];
        if (vnB) pnB = ep[eB + 4];
        if (vA) {
            float w = __uint_as_float(pA.y);
            aA[0] = fmaf(w, bf2f(hA.x & 0xffffu), aA[0]);
            aA[1] = fmaf(w, bf2f(hA.x >> 16), aA[1]);
            aA[2] = fmaf(w, bf2f(hA.y & 0xffffu), aA[2]);
            aA[3] = fmaf(w, bf2f(hA.y >> 16), aA[3]);
            aA[4] = fmaf(w, bf2f(hA.z & 0xffffu), aA[4]);
            aA[5] = fmaf(w, bf2f(hA.z >> 16), aA[5]);
            aA[6] = fmaf(w, bf2f(hA.w & 0xffffu), aA[6]);
            aA[7] = fmaf(w, bf2f(hA.w >> 16), aA[7]);
        }
        if (vB) {
            float w = __uint_as_float(pB.y);
            aB[0] = fmaf(w, bf2f(hB.x & 0xffffu), aB[0]);
            aB[1] = fmaf(w, bf2f(hB.x >> 16), aB[1]);
            aB[2] = fmaf(w, bf2f(hB.y & 0xffffu), aB[2]);
            aB[3] = fmaf(w, bf2f(hB.y >> 16), aB[3]);
            aB[4] = fmaf(w, bf2f(hB.z & 0xffffu), aB[4]);
            aB[5] = fmaf(w, bf2f(hB.z >> 16), aB[5]);
            aB[6] = fmaf(w, bf2f(hB.w & 0xffffu), aB[6]);
            aB[7] = fmaf(w, bf2f(hB.w >> 16), aB[7]);
        }
        eA += 4; eB += 4;
        vA = vnA; vB = vnB;
        pA = pnA; pB = pnB;
    }
#pragma unroll
    for (int j = 0; j < 8; ++j) {
        aA[j] += __shfl_xor(aA[j], 32);
        aA[j] += __shfl_xor(aA[j], 16);
        aB[j] += __shfl_xor(aB[j], 32);
        aB[j] += __shfl_xor(aB[j], 16);
    }
    if (lane < 16) {
        float4 o0 = make_float4(aA[0] + b0.x, aA[1] + b0.y, aA[2] + b0.z, aA[3] + b0.w);
        float4 o1 = make_float4(aA[4] + b1.x, aA[5] + b1.y, aA[6] + b1.z, aA[7] + b1.w);
        if (RELU) {
            o0.x = fmaxf(o0.x, 0.f); o0.y = fmaxf(o0.y, 0.f);
            o0.z = fmaxf(o0.z, 0.f); o0.w = fmaxf(o0.w, 0.f);
            o1.x = fmaxf(o1.x, 0.f); o1.y = fmaxf(o1.y, 0.f);
            o1.z = fmaxf(o1.z, 0.f); o1.w = fmaxf(o1.w, 0.f);
        }
        float* op = &out[(size_t)nA * 128 + l16 * 8];
        *reinterpret_cast<float4*>(op) = o0;
        *reinterpret_cast<float4*>(op + 4) = o1;
    } else if (lane < 32 && nB < N) {
        float4 o0 = make_float4(aB[0] + b0.x, aB[1] + b0.y, aB[2] + b0.z, aB[3] + b0.w);
        float4 o1 = make_float4(aB[4] + b1.x, aB[5] + b1.y, aB[6] + b1.z, aB[7] + b1.w);
        if (RELU) {
            o0.x = fmaxf(o0.x, 0.f); o0.y = fmaxf(o0.y, 0.f);
            o0.z = fmaxf(o0.z, 0.f); o0.w = fmaxf(o0.w, 0.f);
            o1.x = fmaxf(o1.x, 0.f); o1.y = fmaxf(o1.y, 0.f);
            o1.z = fmaxf(o1.z, 0.f); o1.w = fmaxf(o1.w, 0.f);
        }
        float* op = &out[(size_t)nB * 128 + l16 * 8];
        *reinterpret_cast<float4*>(op) = o0;
        *reinterpret_cast<float4*>(op + 4) = o1;
    }
}

// ---------------- aggregate (D=64): 2 nodes/wave x 8 edge-slots x 8 lanes ----------------
template <int RELU>
__global__ void k_agg64(const int* __restrict__ rp, const int* __restrict__ rpe,
                        const uint2* __restrict__ ep, const ushort* __restrict__ H,
                        const float* __restrict__ b, float* __restrict__ out, int N) {
    const int wave = threadIdx.x >> 6;
    const int lane = threadIdx.x & 63;
    const int nA = blockIdx.x * 8 + wave * 2;
    const int nB = nA + 1;
    if (nA >= N) return;
    const int slot = lane >> 3;
    const int l8 = lane & 7;
    const uint4* H4 = reinterpret_cast<const uint4*>(H);

    const float4 b0 = *reinterpret_cast<const float4*>(&b[l8 * 8]);
    const float4 b1 = *reinterpret_cast<const float4*>(&b[l8 * 8 + 4]);

    int eA = rp[nA] + slot, e1A = rpe[nA];
    int eB = 0, e1B = 0;
    if (nB < N) { eB = rp[nB] + slot; e1B = rpe[nB]; }

    float aA[8] = {}, aB[8] = {};
    bool vA = eA < e1A, vB = eB < e1B;
    uint2 pA, pB;
    if (vA) pA = ep[eA];
    if (vB) pB = ep[eB];
    while (vA || vB) {
        uint4 hA, hB;
        if (vA) hA = H4[(size_t)pA.x * 8 + l8];
        if (vB) hB = H4[(size_t)pB.x * 8 + l8];
        const bool vnA = (eA + 8) < e1A, vnB = (eB + 8) < e1B;
        uint2 pnA, pnB;
        if (vnA) pnA = ep[eA + 8];
        if (vnB) pnB = ep[eB + 8];
        if (vA) {
            float w = __uint_as_float(pA.y);
            aA[0] = fmaf(w, bf2f(hA.x & 0xffffu), aA[0]);
            aA[1] = fmaf(w, bf2f(hA.x >> 16), aA[1]);
            aA[2] = fmaf(w, bf2f(hA.y & 0xffffu), aA[2]);
            aA[3] = fmaf(w, bf2f(hA.y >> 16), aA[3]);
            aA[4] = fmaf(w, bf2f(hA.z & 0xffffu), aA[4]);
            aA[5] = fmaf(w, bf2f(hA.z >> 16), aA[5]);
            aA[6] = fmaf(w, bf2f(hA.w & 0xffffu), aA[6]);
            aA[7] = fmaf(w, bf2f(hA.w >> 16), aA[7]);
        }
        if (vB) {
            float w = __uint_as_float(pB.y);
            aB[0] = fmaf(w, bf2f(hB.x & 0xffffu), aB[0]);
            aB[1] = fmaf(w, bf2f(hB.x >> 16), aB[1]);
            aB[2] = fmaf(w, bf2f(hB.y & 0xffffu), aB[2]);
            aB[3] = fmaf(w, bf2f(hB.y >> 16), aB[3]);
            aB[4] = fmaf(w, bf2f(hB.z & 0xffffu), aB[4]);
            aB[5] = fmaf(w, bf2f(hB.z >> 16), aB[5]);
            aB[6] = fmaf(w, bf2f(hB.w & 0xffffu), aB[6]);
            aB[7] = fmaf(w, bf2f(hB.w >> 16), aB[7]);
        }
        eA += 8; eB += 8;
        vA = vnA; vB = vnB;
        pA = pnA; pB = pnB;
    }
#pragma unroll
    for (int j = 0; j < 8; ++j) {
        aA[j] += __shfl_xor(aA[j], 8);
        aA[j] += __shfl_xor(aA[j], 16);
        aA[j] += __shfl_xor(aA[j], 32);
        aB[j] += __shfl_xor(aB[j], 8);
        aB[j] += __shfl_xor(aB[j], 16);
        aB[j] += __shfl_xor(aB[j], 32);
    }
    if (lane < 8) {
        float4 o0 = make_float4(aA[0] + b0.x, aA[1] + b0.y, aA[2] + b0.z, aA[3] + b0.w);
        float4 o1 = make_float4(aA[4] + b1.x, aA[5] + b1.y, aA[6] + b1.z, aA[7] + b1.w);
        if (RELU) {
            o0.x = fmaxf(o0.x, 0.f); o0.y = fmaxf(o0.y, 0.f);
            o0.z = fmaxf(o0.z, 0.f); o0.w = fmaxf(o0.w, 0.f);
            o1.x = fmaxf(o1.x, 0.f); o1.y = fmaxf(o1.y, 0.f);
            o1.z = fmaxf(o1.z, 0.f); o1.w = fmaxf(o1.w, 0.f);
        }
        float* op = &out[(size_t)nA * 64 + l8 * 8];
        *reinterpret_cast<float4*>(op) = o0;
        *reinterpret_cast<float4*>(op + 4) = o1;
    } else if (lane < 16 && nB < N) {
        float4 o0 = make_float4(aB[0] + b0.x, aB[1] + b0.y, aB[2] + b0.z, aB[3] + b0.w);
        float4 o1 = make_float4(aB[4] + b1.x, aB[5] + b1.y, aB[6] + b1.z, aB[7] + b1.w);
        if (RELU) {
            o0.x = fmaxf(o0.x, 0.f); o0.y = fmaxf(o0.y, 0.f);
            o0.z = fmaxf(o0.z, 0.f); o0.w = fmaxf(o0.w, 0.f);
            o1.x = fmaxf(o1.x, 0.f); o1.y = fmaxf(o1.y, 0.f);
            o1.z = fmaxf(o1.z, 0.f); o1.w = fmaxf(o1.w, 0.f);
        }
        float* op = &out[(size_t)nB * 64 + l8 * 8];
        *reinterpret_cast<float4*>(op) = o0;
        *reinterpret_cast<float4*>(op + 4) = o1;
    }
}

// ---------------- launch ----------------

extern "C" void kernel_launch(void* const* d_in, const int* in_sizes, int n_in,
                              void* d_out, int out_size, void* d_ws, size_t ws_size,
                              hipStream_t stream) {
    const float* x  = (const float*)d_in[0];
    const int*   ei = (const int*)d_in[1];
    const float* ew = (const float*)d_in[2];
    const float* W1 = (const float*)d_in[3];
    const float* b1 = (const float*)d_in[4];
    const float* W2 = (const float*)d_in[5];
    const float* b2 = (const float*)d_in[6];
    const float* W3 = (const float*)d_in[7];
    const float* b3 = (const float*)d_in[8];

    const int* src = ei;
    const int* dst = ei + NE;

    // ws layout (~58 MB)
    float*  ws       = (float*)d_ws;
    uint64* degcnt   = (uint64*)ws;                  // NN u64 = 2NN ints
    int*    base_ctr = (int*)(ws + 2 * NN);          // 1 int (zeroed with degcnt)
    int*    rp       = (int*)(ws + 2 * NN + 64);     // NN i
    int*    rpe      = (int*)(ws + 3 * NN + 64);     // NN i
    uint2*  ep       = (uint2*)(ws + 4 * NN + 128);  // NE uint2
    ushort* h1       = (ushort*)(ws + 4 * NN + 128 + 2 * NE); // NN*128 bf16
    ushort* h2       = h1 + (size_t)NN * 128;                 // NN*128 bf16
    ushort* h3       = h1;                                    // NN*64 bf16 (aliases h1)
    ushort* wt1      = h2 + (size_t)NN * 128;        // 128*128 bf16
    ushort* wt2      = wt1 + 128 * 128;              // 128*128 bf16
    ushort* wt3      = wt2 + 128 * 128;              // 64*128 bf16
    int*    cursor   = (int*)h2;                     // NN i (aliases h2; dead before gemm2)

    float* out0 = (float*)d_out;                     // [NN,128]
    float* out1 = out0 + NN * 128;                   // [NN,128]
    float* out2 = out1 + NN * 128;                   // [NN,64]
    float* dinv = out2;                              // NN f scratch (dead until agg64)

    const int B = 256;
    const int NB_SCAN = (NN + 1023) / 1024;          // 98
    const int AGB = (NN + 7) / 8;                    // 12500 agg blocks (8 nodes each)

    // prepW + zero degcnt/base_ctr (one kernel)
    k_prep_zero<<<PWB + ZB, B, 0, stream>>>(W1, W2, W3, wt1, wt2, wt3, (int*)degcnt);

    // merged: layer-1 GEMM; each block appends its 410-edge packed-histogram tail
    k_gemm1_hist<<<GB1, 256, 0, stream>>>(x, wt1, h1, NN, dst, ew, degcnt);

    // single-kernel scan (rp/rpe/cursor/dinv)
    k_scan<<<NB_SCAN, 256, 0, stream>>>(degcnt, rp, rpe, cursor, dinv, base_ctr, NN);
    k_fill<<<(NE + B - 1) / B, B, 0, stream>>>(src, dst, ew, dinv, cursor, ep, NE);

    // ----- layer 1 aggregate -----
    k_agg128<1><<<AGB, 256, 0, stream>>>(rp, rpe, ep, h1, b1, out0, NN);

    // ----- layer 2 -----
    k_gemm_mfma<128><<<GB1, 256, 0, stream>>>(out0, wt2, h2, NN);
    k_agg128<1><<<AGB, 256, 0, stream>>>(rp, rpe, ep, h2, b2, out1, NN);

    // ----- layer 3 -----
    k_gemm_mfma<64><<<GB1, 256, 0, stream>>>(out1, wt3, h3, NN);
    k_agg64<0><<<AGB, 256, 0, stream>>>(rp, rpe, ep, h3, b3, out2, NN);
}